// Round 11
// baseline (4650.566 us; speedup 1.0000x reference)
//
#include <hip/hip_runtime.h>
#include <hip/hip_cooperative_groups.h>

namespace cg = cooperative_groups;

typedef unsigned short u16;
typedef unsigned int u32;
typedef __attribute__((ext_vector_type(8))) short short8;   // 8 x bf16 (4 VGPRs)
typedef __attribute__((ext_vector_type(4))) float float4v;  // 4 x f32

#define DEV static __device__ __forceinline__

DEV float bf2f(u16 u) { u32 x = ((u32)u) << 16; float f; __builtin_memcpy(&f, &x, 4); return f; }
DEV u16 f2bf(float f) {
  u32 u; __builtin_memcpy(&u, &f, 4);
  u = (u + 0x7fffu + ((u >> 16) & 1u)) >> 16;
  return (u16)u;
}
DEV float sigm(float x) { return 1.f / (1.f + __expf(-x)); }

// async global->LDS, 16B per lane; LDS dest = wave-uniform base + lane*16
DEV void gl16(const u16* g, u16* l) {
  __builtin_amdgcn_global_load_lds(
      (const __attribute__((address_space(1))) void*)g,
      (__attribute__((address_space(3))) void*)l, 16, 0, 0);
}

// ============================================================
// Generic GEMM (small cases): C[M,N] = A[M,K](bf16) * B[N,K](bf16 "NK")
// OMODE: 0 = f32 row-major, 3 = f32 + bias + tanh-GELU epilogue (fc1)
// ============================================================
template <int OMODE>
__launch_bounds__(256)
__global__ void gemm_nt(const u16* __restrict__ A, int lda,
                        const u16* __restrict__ B, int ldb,
                        void* __restrict__ Cp, int ldc,
                        int M, int N, int K,
                        const float* __restrict__ bias)
{
  constexpr int PK = 40;
  __shared__ u16 As[128 * PK];
  __shared__ u16 Bs[64 * PK];

  const int tid  = threadIdx.x;
  const int m0   = blockIdx.y * 128;
  const int n0   = blockIdx.x * 64;
  const int wid  = tid >> 6;
  const int lane = tid & 63;
  const int l15  = lane & 15;
  const int quad = lane >> 4;
  const int wm   = (wid >> 1) * 64;
  const int wn   = (wid & 1) * 32;

  float4v acc[4][2];
  const float4v fz = {0.f, 0.f, 0.f, 0.f};
#pragma unroll
  for (int i = 0; i < 4; i++)
#pragma unroll
    for (int j = 0; j < 2; j++) acc[i][j] = fz;

  const int arow = tid >> 2;
  const int akc  = tid & 3;

  const int kt_count = (K + 31) / 32;
  for (int kt = 0; kt < kt_count; ++kt) {
    const int k0 = kt * 32 + akc * 8;
    const bool kok = (k0 < K);
    uint4 av0 = make_uint4(0, 0, 0, 0), av1 = av0, bv = av0;
    int ra = m0 + arow;
    if (kok && ra < M)        av0 = *(const uint4*)(A + (size_t)ra * lda + k0);
    if (kok && ra + 64 < M)   av1 = *(const uint4*)(A + (size_t)(ra + 64) * lda + k0);
    int rb = n0 + arow;
    if (kok && rb < N)        bv  = *(const uint4*)(B + (size_t)rb * ldb + k0);

    __syncthreads();
    *(uint4*)&As[arow * PK + akc * 8]        = av0;
    *(uint4*)&As[(arow + 64) * PK + akc * 8] = av1;
    *(uint4*)&Bs[arow * PK + akc * 8]        = bv;
    __syncthreads();

    short8 af[4], bfr[2];
#pragma unroll
    for (int i = 0; i < 4; i++)
      af[i] = *(const short8*)&As[(wm + i * 16 + l15) * PK + quad * 8];
#pragma unroll
    for (int j = 0; j < 2; j++)
      bfr[j] = *(const short8*)&Bs[(wn + j * 16 + l15) * PK + quad * 8];
#pragma unroll
    for (int i = 0; i < 4; i++)
#pragma unroll
      for (int j = 0; j < 2; j++)
        acc[i][j] = __builtin_amdgcn_mfma_f32_16x16x32_bf16(af[i], bfr[j], acc[i][j], 0, 0, 0);
  }

#pragma unroll
  for (int i = 0; i < 4; i++)
#pragma unroll
    for (int j = 0; j < 2; j++)
#pragma unroll
      for (int e = 0; e < 4; e++) {
        int r = m0 + wm + i * 16 + quad * 4 + e;
        int c = n0 + wn + j * 16 + l15;
        if (r < M && c < N) {
          float v = acc[i][j][e];
          if (OMODE == 0) ((float*)Cp)[(size_t)r * ldc + c] = v;
          else {
            float a = v + bias[c];
            float t = tanhf(0.7978845608028654f * (a + 0.044715f * a * a * a));
            ((float*)Cp)[(size_t)r * ldc + c] = 0.5f * a * (1.f + t);
          }
        }
      }
}

// ============================================================
// Big graph-conv GEMM + fused LN2: BK=64 (16 barrier iters), gl16,
// XOR swizzle, XCD swizzle; writes LN2'd bf16 in GRU g-layout.
// ============================================================
__launch_bounds__(256)
__global__ void k_bigemm(const u16* __restrict__ A,    // Sbf 1024x1024
                         const u16* __restrict__ B,    // h2t 36864x1024
                         const float* __restrict__ b2, const float* __restrict__ g2,
                         const float* __restrict__ be2,
                         u16* __restrict__ Gg)
{
  __shared__ u16 As[128 * 64];
  __shared__ u16 Bs[96 * 64];
  __shared__ float stats[2][2][128];

  const int tid  = threadIdx.x;
  const int bid  = blockIdx.x;
  const int xcd  = bid & 7;
  const int jj   = bid >> 3;
  const int m0   = (jj & 7) * 128;
  const int rt   = xcd + 8 * (jj >> 3);

  const int wid  = tid >> 6;
  const int lane = tid & 63;
  const int l15  = lane & 15;
  const int quad = lane >> 4;
  const int wm   = (wid >> 1) * 64;
  const int wn   = (wid & 1) * 48;
  const int wni  = wid & 1;

  const int srow8 = lane >> 3;
  const int sw8   = ((lane & 7) ^ srow8) * 8;

  const u16* abase = A + (size_t)(m0 + wid * 8 + srow8) * 1024 + sw8;
  const u16* bbase = B + (size_t)(rt * 96 + wid * 8 + srow8) * 1024 + sw8;

  float4v acc[4][3];
  const float4v fz = {0.f, 0.f, 0.f, 0.f};
#pragma unroll
  for (int i = 0; i < 4; i++)
#pragma unroll
    for (int j = 0; j < 3; j++) acc[i][j] = fz;

  for (int kt = 0; kt < 16; ++kt) {
    const int ko = kt * 64;
#pragma unroll
    for (int c = 0; c < 4; c++)
      gl16(abase + (size_t)c * 32 * 1024 + ko, &As[(c * 32 + wid * 8) * 64]);
#pragma unroll
    for (int c = 0; c < 3; c++)
      gl16(bbase + (size_t)c * 32 * 1024 + ko, &Bs[(c * 32 + wid * 8) * 64]);
    __syncthreads();
#pragma unroll
    for (int k32 = 0; k32 < 2; k32++) {
      const int swr = ((quad + 4 * k32) ^ (l15 & 7)) * 8;
      short8 af[4], bf[3];
#pragma unroll
      for (int i = 0; i < 4; i++)
        af[i] = *(const short8*)&As[(wm + i * 16 + l15) * 64 + swr];
#pragma unroll
      for (int j = 0; j < 3; j++)
        bf[j] = *(const short8*)&Bs[(wn + j * 16 + l15) * 64 + swr];
#pragma unroll
      for (int i = 0; i < 4; i++)
#pragma unroll
        for (int j = 0; j < 3; j++)
          acc[i][j] = __builtin_amdgcn_mfma_f32_16x16x32_bf16(af[i], bf[j], acc[i][j], 0, 0, 0);
    }
    __syncthreads();
  }

  // ---- fused LN2 epilogue ----
  float b2v[3], g2v[3], bev[3];
#pragma unroll
  for (int j = 0; j < 3; j++) {
    int c = wn + j * 16 + l15;
    b2v[j] = b2[c]; g2v[j] = g2[c]; bev[j] = be2[c];
  }
#pragma unroll
  for (int i = 0; i < 4; i++)
#pragma unroll
    for (int e = 0; e < 4; e++) {
      float s = 0.f, ss = 0.f;
#pragma unroll
      for (int j = 0; j < 3; j++) {
        float v = acc[i][j][e] + b2v[j];
        acc[i][j][e] = v;
        s += v; ss += v * v;
      }
      s += __shfl_xor(s, 1); ss += __shfl_xor(ss, 1);
      s += __shfl_xor(s, 2); ss += __shfl_xor(ss, 2);
      s += __shfl_xor(s, 4); ss += __shfl_xor(ss, 4);
      s += __shfl_xor(s, 8); ss += __shfl_xor(ss, 8);
      if (l15 == 0) {
        int rl = wm + i * 16 + quad * 4 + e;
        stats[wni][0][rl] = s;
        stats[wni][1][rl] = ss;
      }
    }
  __syncthreads();
#pragma unroll
  for (int i = 0; i < 4; i++)
#pragma unroll
    for (int e = 0; e < 4; e++) {
      int rl = wm + i * 16 + quad * 4 + e;
      int m = m0 + rl;
      if (m < 1000) {
        float ts  = stats[0][0][rl] + stats[1][0][rl];
        float tss = stats[0][1][rl] + stats[1][1][rl];
        float mean = ts * (1.f / 96.f);
        float var  = tss * (1.f / 96.f) - mean * mean;
        float isd  = rsqrtf(var + 1e-5f);
#pragma unroll
        for (int j = 0; j < 3; j++) {
          int c = wn + j * 16 + l15;
          Gg[(size_t)rt * 96000 + (size_t)m * 96 + c] =
              f2bf((acc[i][j][e] - mean) * isd * g2v[j] + bev[j]);
        }
      }
    }
}

// ============================================================
// GRU tile device function (shared by fallback kernels + persistent kernel).
// BM=128, 32 cols/gate. K=192 phases BK=64; K=96 X-phase BK=32.
// ============================================================
template <int KX, bool POOL>
DEV void gru_tile(u16* As, u16* Bs,
                  int m0, int c0,
                  const u16* __restrict__ Xin, int ldx,
                  const u16* __restrict__ Win,
                  const u16* __restrict__ Hin,
                  const u16* __restrict__ Whh,
                  const float* __restrict__ bih, const float* __restrict__ bhh,
                  u16* __restrict__ Hout,
                  const float* __restrict__ att_w,
                  float* __restrict__ score_acc,
                  float* __restrict__ score_zero,
                  const u16* __restrict__ Hpool,
                  const float* __restrict__ score_rd,
                  const float* __restrict__ Mrd, const float* __restrict__ Lrd,
                  float* __restrict__ Mwr, float* __restrict__ Lwr,
                  float* __restrict__ Nvp,
                  int t0, int pm)
{
  const int tid  = threadIdx.x;
  const int wid  = tid >> 6;
  const int lane = tid & 63;
  const int l15  = lane & 15;
  const int quad = lane >> 4;
  const int wm   = wid * 32;

  // ---- folded pool (layer0, previous timestep) ----
  if (!POOL && pm) {
#pragma unroll
    for (int k = 0; k < 16; k++) {
      int idx = k * 256 + tid;
      int ql = idx >> 5, cl = idx & 31;
      int q = m0 + ql, c = c0 + cl;
      size_t nidx = (size_t)q * 192 + c;
      float s = score_rd[q];
      float hnew = bf2f(Hpool[nidx]);
      float so, wnf, prev;
      if (pm == 1) { so = 0.f; wnf = 1.f; prev = 0.f; }
      else {
        float Mo = Mrd[q];
        float Mn = fmaxf(Mo, s);
        so = __expf(Mo - Mn); wnf = __expf(s - Mn);
        prev = Nvp[nidx];
      }
      Nvp[nidx] = prev * so + wnf * hnew;
    }
    if (c0 == 0 && tid < 128) {
      int q = m0 + tid;
      float s = score_rd[q];
      if (pm == 1) { Mwr[q] = s; Lwr[q] = 1.f; }
      else {
        float Mo = Mrd[q], Mn = fmaxf(Mo, s);
        Mwr[q] = Mn;
        Lwr[q] = Lrd[q] * __expf(Mo - Mn) + __expf(s - Mn);
      }
    }
  }
  if (POOL && c0 == 0 && tid < 128) score_zero[m0 + tid] = 0.f;

  const int srow8 = lane >> 3;
  const int sw8   = ((lane & 7) ^ srow8) * 8;
  const int srow4 = lane >> 2;
  const int sw4   = ((lane & 3) ^ ((lane >> 3) & 3)) * 8;

  float4v aR[2][2], aZ[2][2], aXN[2][2], aHN[2][2];
  const float4v fz = {0.f, 0.f, 0.f, 0.f};
#pragma unroll
  for (int i = 0; i < 2; i++)
#pragma unroll
    for (int j = 0; j < 2; j++) { aR[i][j] = fz; aZ[i][j] = fz; aXN[i][j] = fz; aHN[i][j] = fz; }

  // ---- phase X ----
  if (KX == 96) {
    const u16* ax0 = Xin + (size_t)(m0 + wid * 16 + srow4) * ldx + sw4;
    const u16* ax1 = Xin + (size_t)(m0 + 64 + wid * 16 + srow4) * ldx + sw4;
    const int b0 = wid * 16 + srow4;
    const u16* bx0 = Win + (size_t)((b0 >> 5) * 192 + c0 + (b0 & 31)) * 96 + sw4;
    const int b1 = 64 + wid * 16 + srow4;
    const u16* bx1 = Win + (size_t)(384 + c0 + (b1 & 31)) * 96 + sw4;
    u16* asl0 = &As[(wid * 16) * 32];
    u16* asl1 = &As[(64 + wid * 16) * 32];
    u16* bsl0 = &Bs[(wid * 16) * 32];
    u16* bsl1 = &Bs[(64 + wid * 16) * 32];
    const int swa = (quad ^ ((l15 >> 1) & 3)) * 8;
#pragma unroll
    for (int kt = 0; kt < 3; ++kt) {
      const int ko = kt * 32;
      gl16(ax0 + ko, asl0); gl16(ax1 + ko, asl1);
      gl16(bx0 + ko, bsl0);
      if (wid < 2) gl16(bx1 + ko, bsl1);
      __syncthreads();
      short8 af[2], bR[2], bZ[2], bN[2];
#pragma unroll
      for (int i = 0; i < 2; i++)
        af[i] = *(const short8*)&As[(wm + i * 16 + l15) * 32 + swa];
#pragma unroll
      for (int j = 0; j < 2; j++) {
        bR[j] = *(const short8*)&Bs[(j * 16 + l15) * 32 + swa];
        bZ[j] = *(const short8*)&Bs[(32 + j * 16 + l15) * 32 + swa];
        bN[j] = *(const short8*)&Bs[(64 + j * 16 + l15) * 32 + swa];
      }
#pragma unroll
      for (int i = 0; i < 2; i++)
#pragma unroll
        for (int j = 0; j < 2; j++) {
          aR[i][j]  = __builtin_amdgcn_mfma_f32_16x16x32_bf16(af[i], bR[j], aR[i][j], 0, 0, 0);
          aZ[i][j]  = __builtin_amdgcn_mfma_f32_16x16x32_bf16(af[i], bZ[j], aZ[i][j], 0, 0, 0);
          aXN[i][j] = __builtin_amdgcn_mfma_f32_16x16x32_bf16(af[i], bN[j], aXN[i][j], 0, 0, 0);
        }
      __syncthreads();
    }
  } else {
    const u16* abase = Xin + (size_t)(m0 + wid * 8 + srow8) * 192 + sw8;
    const u16* bbase = Win + (size_t)(c0 + wid * 8 + srow8) * 192 + sw8;
#pragma unroll
    for (int kt = 0; kt < 3; ++kt) {
      const int ko = kt * 64;
#pragma unroll
      for (int c = 0; c < 4; c++)
        gl16(abase + (size_t)c * 32 * 192 + ko, &As[(c * 32 + wid * 8) * 64]);
#pragma unroll
      for (int c = 0; c < 3; c++)
        gl16(bbase + (size_t)c * 192 * 192 + ko, &Bs[(c * 32 + wid * 8) * 64]);
      __syncthreads();
#pragma unroll
      for (int k32 = 0; k32 < 2; k32++) {
        const int swr = ((quad + 4 * k32) ^ (l15 & 7)) * 8;
        short8 af[2], bR[2], bZ[2], bN[2];
#pragma unroll
        for (int i = 0; i < 2; i++)
          af[i] = *(const short8*)&As[(wm + i * 16 + l15) * 64 + swr];
#pragma unroll
        for (int j = 0; j < 2; j++) {
          bR[j] = *(const short8*)&Bs[(j * 16 + l15) * 64 + swr];
          bZ[j] = *(const short8*)&Bs[(32 + j * 16 + l15) * 64 + swr];
          bN[j] = *(const short8*)&Bs[(64 + j * 16 + l15) * 64 + swr];
        }
#pragma unroll
        for (int i = 0; i < 2; i++)
#pragma unroll
          for (int j = 0; j < 2; j++) {
            aR[i][j]  = __builtin_amdgcn_mfma_f32_16x16x32_bf16(af[i], bR[j], aR[i][j], 0, 0, 0);
            aZ[i][j]  = __builtin_amdgcn_mfma_f32_16x16x32_bf16(af[i], bZ[j], aZ[i][j], 0, 0, 0);
            aXN[i][j] = __builtin_amdgcn_mfma_f32_16x16x32_bf16(af[i], bN[j], aXN[i][j], 0, 0, 0);
          }
      }
      __syncthreads();
    }
  }
  // ---- phase H: K=192, BK=64 x 3 ----
  if (!t0) {
    const u16* abase = Hin + (size_t)(m0 + wid * 8 + srow8) * 192 + sw8;
    const u16* bbase = Whh + (size_t)(c0 + wid * 8 + srow8) * 192 + sw8;
#pragma unroll
    for (int kt = 0; kt < 3; ++kt) {
      const int ko = kt * 64;
#pragma unroll
      for (int c = 0; c < 4; c++)
        gl16(abase + (size_t)c * 32 * 192 + ko, &As[(c * 32 + wid * 8) * 64]);
#pragma unroll
      for (int c = 0; c < 3; c++)
        gl16(bbase + (size_t)c * 192 * 192 + ko, &Bs[(c * 32 + wid * 8) * 64]);
      __syncthreads();
#pragma unroll
      for (int k32 = 0; k32 < 2; k32++) {
        const int swr = ((quad + 4 * k32) ^ (l15 & 7)) * 8;
        short8 af[2], bR[2], bZ[2], bN[2];
#pragma unroll
        for (int i = 0; i < 2; i++)
          af[i] = *(const short8*)&As[(wm + i * 16 + l15) * 64 + swr];
#pragma unroll
        for (int j = 0; j < 2; j++) {
          bR[j] = *(const short8*)&Bs[(j * 16 + l15) * 64 + swr];
          bZ[j] = *(const short8*)&Bs[(32 + j * 16 + l15) * 64 + swr];
          bN[j] = *(const short8*)&Bs[(64 + j * 16 + l15) * 64 + swr];
        }
#pragma unroll
        for (int i = 0; i < 2; i++)
#pragma unroll
          for (int j = 0; j < 2; j++) {
            aR[i][j]  = __builtin_amdgcn_mfma_f32_16x16x32_bf16(af[i], bR[j], aR[i][j], 0, 0, 0);
            aZ[i][j]  = __builtin_amdgcn_mfma_f32_16x16x32_bf16(af[i], bZ[j], aZ[i][j], 0, 0, 0);
            aHN[i][j] = __builtin_amdgcn_mfma_f32_16x16x32_bf16(af[i], bN[j], aHN[i][j], 0, 0, 0);
          }
      }
      __syncthreads();
    }
  }

  // ---- epilogue: gates + state write (+ pooling partials) ----
  float ps[2][4];
  if (POOL) {
#pragma unroll
    for (int i = 0; i < 2; i++)
#pragma unroll
      for (int e = 0; e < 4; e++) ps[i][e] = 0.f;
  }
#pragma unroll
  for (int j = 0; j < 2; ++j) {
    const int c = c0 + j * 16 + l15;
    const float brz = bih[c] + bhh[c];
    const float bzz = bih[192 + c] + bhh[192 + c];
    const float bxn = bih[384 + c];
    const float bhn = bhh[384 + c];
    const float aw  = POOL ? att_w[c] : 0.f;
#pragma unroll
    for (int i = 0; i < 2; ++i)
#pragma unroll
      for (int e = 0; e < 4; ++e) {
        const int row = m0 + wm + i * 16 + quad * 4 + e;
        float rg  = sigm(aR[i][j][e] + brz);
        float zg  = sigm(aZ[i][j][e] + bzz);
        float hnv = bhn + (t0 ? 0.f : aHN[i][j][e]);
        float ng  = tanhf(aXN[i][j][e] + bxn + rg * hnv);
        float hold = t0 ? 0.f : bf2f(Hin[(size_t)row * 192 + c]);
        float hnew = (1.f - zg) * ng + zg * hold;
        Hout[(size_t)row * 192 + c] = f2bf(hnew);
        if (POOL) ps[i][e] += hnew * aw;
      }
  }
  if (POOL) {
#pragma unroll
    for (int i = 0; i < 2; ++i)
#pragma unroll
      for (int e = 0; e < 4; ++e) {
        float v = ps[i][e];
        v += __shfl_xor(v, 1); v += __shfl_xor(v, 2);
        v += __shfl_xor(v, 4); v += __shfl_xor(v, 8);
        if (l15 == 0) atomicAdd(&score_acc[m0 + wm + i * 16 + quad * 4 + e], v);
      }
  }
}

// ---- fallback per-step kernel (same behavior as R10) ----
template <int KX, bool POOL>
__launch_bounds__(256)
__global__ void k_gru(const u16* __restrict__ Xin, int ldx,
                      const u16* __restrict__ Win,
                      const u16* __restrict__ Hin,
                      const u16* __restrict__ Whh,
                      const float* __restrict__ bih, const float* __restrict__ bhh,
                      u16* __restrict__ Hout,
                      const float* __restrict__ att_w,
                      float* __restrict__ score_acc, float* __restrict__ score_zero,
                      const u16* __restrict__ Hpool, const float* __restrict__ score_rd,
                      const float* __restrict__ Mrd, const float* __restrict__ Lrd,
                      float* __restrict__ Mwr, float* __restrict__ Lwr,
                      float* __restrict__ Nvp, int t0, int pm)
{
  __shared__ u16 As[128 * 64];
  __shared__ u16 Bs[96 * 64];
  gru_tile<KX, POOL>(As, Bs, blockIdx.y * 128, blockIdx.x * 32,
                     Xin, ldx, Win, Hin, Whh, bih, bhh, Hout, att_w,
                     score_acc, score_zero, Hpool, score_rd, Mrd, Lrd, Mwr, Lwr, Nvp, t0, pm);
}

// ---- persistent cooperative GRU: all 12 steps, grid-wide sync ----
struct GruArgs {
  const u16 *Gg, *Wih0, *Whh0, *Wih1, *Whh1;
  const float *bih0, *bhh0, *bih1, *bhh1, *att_w;
  u16 *h0a, *h0b, *h1a, *h1b;
  float *M0, *M1, *L0, *L1, *s0, *s1;
  float* Nv;
};

__launch_bounds__(256, 4)
__global__ void k_grup(GruArgs a)
{
  __shared__ u16 As[128 * 64];
  __shared__ u16 Bs[96 * 64];
  cg::grid_group grid = cg::this_grid();
  u16* h0buf[2] = { a.h0a, a.h0b };
  u16* h1buf[2] = { a.h1a, a.h1b };
  float* Mb[2] = { a.M0, a.M1 };
  float* Lb[2] = { a.L0, a.L1 };
  float* sc[2] = { a.s0, a.s1 };

  for (int t = 0; t < 12; ++t) {
    const int pm = (t == 0) ? 0 : (t == 1 ? 1 : 2);
    for (int tile = blockIdx.x; tile < 1500; tile += gridDim.x) {
      int m0 = (tile % 250) * 128, c0 = (tile / 250) * 32;
      gru_tile<96, false>(As, Bs, m0, c0,
          a.Gg + t * 96, 1152, a.Wih0, h0buf[t & 1], a.Whh0, a.bih0, a.bhh0, h0buf[(t & 1) ^ 1],
          nullptr, nullptr, nullptr,
          h1buf[t & 1], sc[(t + 1) & 1], Mb[(t + 1) & 1], Lb[(t + 1) & 1],
          Mb[t & 1], Lb[t & 1], a.Nv, t == 0, pm);
    }
    grid.sync();
    for (int tile = blockIdx.x; tile < 1500; tile += gridDim.x) {
      int m0 = (tile % 250) * 128, c0 = (tile / 250) * 32;
      gru_tile<192, true>(As, Bs, m0, c0,
          h0buf[(t & 1) ^ 1], 192, a.Wih1, h1buf[t & 1], a.Whh1, a.bih1, a.bhh1, h1buf[(t & 1) ^ 1],
          a.att_w, sc[t & 1], sc[(t + 1) & 1],
          nullptr, nullptr, nullptr, nullptr, nullptr, nullptr, nullptr,
          t == 0, 0);
    }
    grid.sync();
  }
}

// final pool (tp = 11): 8 q per 256-thread block
__launch_bounds__(256)
__global__ void k_pool(const u16* __restrict__ H, const float* __restrict__ score_rd,
                       const float* __restrict__ Mrd, const float* __restrict__ Lrd,
                       float* __restrict__ Lwr, float* __restrict__ Nv)
{
  const int base = blockIdx.x * 1536;
  const int tid  = threadIdx.x;
#pragma unroll
  for (int k = 0; k < 6; k++) {
    const int idx = base + tid + k * 256;
    const int q = idx / 192;
    const float s = score_rd[q];
    const float Mo = Mrd[q];
    const float Mn = fmaxf(Mo, s);
    const float so = __expf(Mo - Mn);
    const float wn = __expf(s - Mn);
    Nv[idx] = Nv[idx] * so + wn * bf2f(H[idx]);
  }
  if (tid < 8) {
    const int q = blockIdx.x * 8 + tid;
    const float s = score_rd[q];
    const float Mo = Mrd[q];
    const float Mn = fmaxf(Mo, s);
    Lwr[q] = Lrd[q] * __expf(Mo - Mn) + __expf(s - Mn);
  }
}

// ============================================================
// H2 GEMM: h2t[(r*96+c2)*1024+n] = Hln @ W2 (analytic LN1 in A-staging)
// ============================================================
__launch_bounds__(256)
__global__ void k_h2gemm(const float* __restrict__ yt, const float4* __restrict__ cwpk,
                         const u16* __restrict__ W2s, const float* __restrict__ consts,
                         u16* __restrict__ h2t)
{
  constexpr int PK = 40;
  __shared__ u16 As[128 * PK];
  __shared__ u16 Bs[96 * PK];
  __shared__ u16 Ts[96 * 136];

  const int tid  = threadIdx.x;
  const int m0   = blockIdx.x * 128;
  const int wid  = tid >> 6;
  const int lane = tid & 63;
  const int l15  = lane & 15;
  const int quad = lane >> 4;
  const int wm   = (wid >> 1) * 64;
  const int wn   = (wid & 1) * 48;

  const float P = consts[0], Q = consts[1], VW = consts[2], CWB = consts[3], VB = consts[4];

  const int arow = tid >> 2;
  const int akc  = tid & 3;

  float yv[2], mu[2], iv[2];
#pragma unroll
  for (int rr = 0; rr < 2; rr++) {
    int i = m0 + arow + rr * 64;
    int r = i / 1000, n = i - r * 1000;
    float y = yt[n * 384 + r];
    yv[rr] = y;
    mu[rr] = y * P + Q;
    iv[rr] = rsqrtf(y * y * VW + 2.f * y * CWB + VB + 1e-5f);
  }

  float4v acc[4][3];
  const float4v fz = {0.f, 0.f, 0.f, 0.f};
#pragma unroll
  for (int i = 0; i < 4; i++)
#pragma unroll
    for (int j = 0; j < 3; j++) acc[i][j] = fz;

  uint4 asave[2][3];
  const bool has2 = (arow < 32);

  for (int kt = 0; kt < 6; ++kt) {
    const int k0 = kt * 32 + akc * 8;
    uint4 av[2];
    if (kt < 3) {
#pragma unroll
      for (int rr = 0; rr < 2; rr++) {
        u16 hb[8];
#pragma unroll
        for (int e = 0; e < 8; e++) {
          float4 cw = cwpk[k0 + e];
          float t = yv[rr] * cw.x + cw.y - mu[rr];
          float h = fmaxf(t * iv[rr] * cw.z + cw.w, 0.f);
          hb[e] = f2bf(h);
        }
        __builtin_memcpy(&av[rr], hb, 16);
        asave[rr][kt] = av[rr];
      }
    } else {
      av[0] = asave[0][kt - 3];
      av[1] = asave[1][kt - 3];
    }
    uint4 bv0 = *(const uint4*)(W2s + (size_t)arow * 192 + k0);
    uint4 bv1 = make_uint4(0, 0, 0, 0);
    if (has2) bv1 = *(const uint4*)(W2s + (size_t)(arow + 64) * 192 + k0);

    __syncthreads();
    *(uint4*)&As[arow * PK + akc * 8]        = av[0];
    *(uint4*)&As[(arow + 64) * PK + akc * 8] = av[1];
    *(uint4*)&Bs[arow * PK + akc * 8]        = bv0;
    if (has2) *(uint4*)&Bs[(arow + 64) * PK + akc * 8] = bv1;
    __syncthreads();

    short8 af[4], bfr[3];
#pragma unroll
    for (int i = 0; i < 4; i++)
      af[i] = *(const short8*)&As[(wm + i * 16 + l15) * PK + quad * 8];
#pragma unroll
    for (int j = 0; j < 3; j++)
      bfr[j] = *(const short8*)&Bs[(wn + j * 16 + l15) * PK + quad * 8];
#pragma unroll
    for (int i = 0; i < 4; i++)
#pragma unroll
      for (int j = 0; j < 3; j++)
        acc[i][j] = __builtin_amdgcn_mfma_f32_16x16x32_bf16(af[i], bfr[j], acc[i][j], 0, 0, 0);
  }

#pragma unroll
  for (int i = 0; i < 4; i++)
#pragma unroll
    for (int j = 0; j < 3; j++)
#pragma unroll
      for (int e = 0; e < 4; e++) {
        int rowl = wm + i * 16 + quad * 4 + e;
        int c2   = wn + j * 16 + l15;
        Ts[c2 * 136 + rowl] = f2bf(acc[i][j][e]);
      }
  __syncthreads();
#pragma unroll
  for (int u = tid; u < 1536; u += 256) {
    int c2 = u >> 4, ch = u & 15;
    int iidx0 = m0 + ch * 8;
    int r = iidx0 / 1000, n0 = iidx0 - r * 1000;
    *(uint4*)(h2t + (size_t)(r * 96 + c2) * 1024 + n0) = *(const uint4*)&Ts[c2 * 136 + ch * 8];
  }
}

// ============================================================
// prep: f32 -> bf16 conversions + W1/b1 moment stats + W2 split + cw pack
// ============================================================
__launch_bounds__(256)
__global__ void k_prep(const float* x, const float* fus_W,
                       const float* Wih0, const float* Whh0,
                       const float* Wih1, const float* Whh1,
                       const float* gcn_W1, const float* gcn_b1,
                       const float* gcn_W2, const float* ln1g, const float* ln1b,
                       u16* xbf, u16* fusWbf, u16* Wih0b, u16* Whh0b, u16* Wih1b, u16* Whh1b,
                       u16* W2s, float4* cwpk, float* consts)
{
  long o = (long)blockIdx.x * 256 + threadIdx.x;
  if (o < 384000) xbf[o] = f2bf(x[o]);
  else if ((o -= 384000) < 32000) fusWbf[o] = f2bf(fus_W[o]);
  else if ((o -= 32000) < 55296)  Wih0b[o] = f2bf(Wih0[o]);
  else if ((o -= 55296) < 110592) Whh0b[o] = f2bf(Whh0[o]);
  else if ((o -= 110592) < 110592) Wih1b[o] = f2bf(Wih1[o]);
  else if ((o -= 110592) < 110592) Whh1b[o] = f2bf(Whh1[o]);
  else if ((o -= 110592) < 9216) {
    int c2 = (int)o / 96, c = (int)o - c2 * 96;
    float wv = gcn_W2[c * 96 + c2];
    u16 hi = f2bf(wv);
    u16 lo = f2bf(wv - bf2f(hi));
    W2s[c2 * 192 + c] = hi;
    W2s[c2 * 192 + 96 + c] = lo;
  }
  else if ((o -= 9216) < 96) {
    int c = (int)o;
    float4 cw;
    cw.x = gcn_W1[c]; cw.y = gcn_b1[c]; cw.z = ln1g[c]; cw.w = ln1b[c];
    cwpk[c] = cw;
  }
  if (blockIdx.x == 0 && threadIdx.x == 0) {
    float sw = 0, sb = 0, sww = 0, swb = 0, sbb = 0;
    for (int c = 0; c < 96; c++) {
      float wv = gcn_W1[c], b = gcn_b1[c];
      sw += wv; sb += b; sww += wv * wv; swb += wv * b; sbb += b * b;
    }
    float P = sw / 96.f, Q = sb / 96.f;
    consts[0] = P; consts[1] = Q;
    consts[2] = sww / 96.f - P * P;
    consts[3] = swb / 96.f - P * Q;
    consts[4] = sbb / 96.f - Q * Q;
  }
}

// zero-fill: h2t K-pad columns (1000..1023) + both score buffers
__launch_bounds__(256)
__global__ void k_zero(u16* __restrict__ h2t, float* __restrict__ score0,
                       float* __restrict__ score1)
{
  int idx = blockIdx.x * 256 + threadIdx.x;
  if (idx < 110592) {
    int row = idx / 3, p = idx - row * 3;
    *(uint4*)(h2t + (size_t)row * 1024 + 1000 + p * 8) = make_uint4(0, 0, 0, 0);
  } else if ((idx -= 110592) < 32000) {
    score0[idx] = 0.f;
  } else if ((idx -= 32000) < 32000) {
    score1[idx] = 0.f;
  }
}

// fc1W (192x192 f32) -> split-bf16 B' (192 x 576): [wh | wl | wh]
__launch_bounds__(256)
__global__ void k_w1split(const float* __restrict__ fc1W, u16* __restrict__ w1s)
{
  int idx = blockIdx.x * 256 + threadIdx.x;
  if (idx >= 192 * 192) return;
  int n = idx / 192, k = idx - n * 192;
  float w = fc1W[idx];
  u16 hi = f2bf(w);
  u16 lo = f2bf(w - bf2f(hi));
  w1s[(size_t)n * 576 + k]       = hi;
  w1s[(size_t)n * 576 + 192 + k] = lo;
  w1s[(size_t)n * 576 + 384 + k] = hi;
}

// ============================================================
// per-row: Aadp softmax row + the 3 candidate graphs (bf16) + row sums
// ============================================================
__launch_bounds__(256)
__global__ void k_adjrow(const float* __restrict__ A, const float* __restrict__ FSP,
                         const float* __restrict__ DSP, const float* __restrict__ E1,
                         const float* __restrict__ E2,
                         const float* beta1, const float* beta2,
                         u16* __restrict__ G, float* __restrict__ rowsums)
{
  __shared__ float z[1000];
  __shared__ float red[256];
  const int n = blockIdx.x, tid = threadIdx.x;

  float e1r[10];
#pragma unroll
  for (int d = 0; d < 10; d++) e1r[d] = E1[n * 10 + d];

  float lmax = -1e30f;
  for (int m = tid; m < 1000; m += 256) {
    float s = 0;
#pragma unroll
    for (int d = 0; d < 10; d++) s += e1r[d] * E2[m * 10 + d];
    s = fmaxf(s, 0.f);
    z[m] = s;
    lmax = fmaxf(lmax, s);
  }
  red[tid] = lmax; __syncthreads();
  for (int st = 128; st > 0; st >>= 1) { if (tid < st) red[tid] = fmaxf(red[tid], red[tid + st]); __syncthreads(); }
  const float mx = red[0]; __syncthreads();

  float lsum = 0;
  for (int m = tid; m < 1000; m += 256) { float e = __expf(z[m] - mx); z[m] = e; lsum += e; }
  red[tid] = lsum; __syncthreads();
  for (int st = 128; st > 0; st >>= 1) { if (tid < st) red[tid] += red[tid + st]; __syncthreads(); }
  const float inv = 1.f / red[0]; __syncthreads();

  const float w1 = sigm(beta1[0]);
  const float w2 = sigm(beta2[0]);
  float s0 = 0, s1 = 0, s2 = 0;
  for (int m = tid; m < 1000; m += 256) {
    float aadp = z[m] * inv;
    float a = A[n * 1000 + m], f = FSP[n * 1000 + m], dd = DSP[n * 1000 + m];
    float g0 = 0.5f * a + 0.5f * aadp;
    float g1 = w1 * a + (1.f - w1) * f;
    float g2 = w2 * a + (1.f - w2) * dd;
    G[0 * 1000000 + n * 1000 + m] = f2bf(g0);
    G[1 * 1000000 + n * 1000 + m] = f2bf(g1);
    G[2 * 1000000 + n * 1000 + m] = f2bf(g2);
    s0 += g0; s1 += g1; s2 += g2;
  }
  red[tid] = s0; __syncthreads();
  for (int st = 128; st > 0; st >>= 1) { if (tid < st) red[tid] += red[tid + st]; __syncthreads(); }
  if (tid == 0) rowsums[n] = red[0];
  __syncthreads();
  red[tid] = s1; __syncthreads();
  for (int st = 128; st > 0; st >>= 1) { if (tid < st) red[tid] += red[tid + st]; __syncthreads(); }
  if (tid == 0) rowsums[1000 + n] = red[0];
  __syncthreads();
  red[tid] = s2; __syncthreads();
  for (int st = 128; st > 0; st >>= 1) { if (tid < st) red[tid] += red[tid + st]; __syncthreads(); }
  if (tid == 0) rowsums[2000 + n] = red[0];
}

// sc[k] = mean_n( sum_a tanh(P[k,n,a]+fus_b[a]) * fus_v[a] )
__launch_bounds__(256)
__global__ void k_sc(const float* __restrict__ P, const float* fus_b, const float* fus_v, float* sc)
{
  __shared__ float red[256];
  const int k = blockIdx.x, tid = threadIdx.x;
  float local = 0;
  for (int n = tid; n < 1000; n += 256) {
    const float* p = P + (size_t)(k * 1000 + n) * 32;
    float s = 0;
#pragma unroll
    for (int a = 0; a < 32; a++) s += tanhf(p[a] + fus_b[a]) * fus_v[a];
    local += s;
  }
  red[tid] = local; __syncthreads();
  for (int st = 128; st > 0; st >>= 1) { if (tid < st) red[tid] += red[tid + st]; __syncthreads(); }
  if (tid == 0) sc[k] = red[0] * (1.f / 1000.f);
}

__launch_bounds__(256)
__global__ void k_alpha(const float* sc, const float* rowsums, float* alpha_out, float* dinv)
{
  __shared__ float al[3];
  const int tid = threadIdx.x;
  if (tid == 0) {
    float m = fmaxf(sc[0], fmaxf(sc[1], sc[2]));
    float e0 = __expf(sc[0] - m), e1 = __expf(sc[1] - m), e2 = __expf(sc[2] - m);
    float inv = 1.f / (e0 + e1 + e2);
    al[0] = e0 * inv; al[1] = e1 * inv; al[2] = e2 * inv;
    alpha_out[0] = al[0]; alpha_out[1] = al[1]; alpha_out[2] = al[2];
  }
  __syncthreads();
  const float a0 = al[0], a1 = al[1], a2 = al[2];
  for (int n = tid; n < 1000; n += 256) {
    float d = a0 * rowsums[n] + a1 * rowsums[1000 + n] + a2 * rowsums[2000 + n] + 1.0f;
    dinv[n] = rsqrtf(fmaxf(d, 1e-12f));
  }
}

// S_hat -> Sbf with 1024 K-pad stride (pad cols zeroed)
__launch_bounds__(256)
__global__ void k_shat(const u16* __restrict__ G, const float* alpha, const float* dinv,
                       u16* __restrict__ S)
{
  int idx = blockIdx.x * 256 + threadIdx.x;
  if (idx >= 1024000) return;
  int i = idx >> 10, j = idx & 1023;
  u16 val = 0;
  if (j < 1000) {
    const float a0 = alpha[0], a1 = alpha[1], a2 = alpha[2];
    int g = i * 1000 + j;
    float mg = a0 * bf2f(G[g]) + a1 * bf2f(G[1000000 + g]) + a2 * bf2f(G[2000000 + g]);
    if (i == j) mg += 1.0f;
    val = f2bf(mg * dinv[i] * dinv[j]);
  }
  S[(size_t)i * 1024 + j] = val;
}

// ctx = Nv/L, split to hi/lo bf16, pack A' rows [ch | ch | cl] (K=576)
__launch_bounds__(256)
__global__ void k_ctxsplit(const float* __restrict__ Nv, const float* __restrict__ Lbuf,
                           u16* __restrict__ ctxs)
{
  const int i = blockIdx.x * 256 + threadIdx.x;
  if (i >= 32000 * 192) return;
  const int q = i / 192, c = i - q * 192;
  float v = Nv[i] / Lbuf[q];
  u16 hi = f2bf(v);
  u16 lo = f2bf(v - bf2f(hi));
  u16* row = ctxs + (size_t)q * 576;
  row[c] = hi; row[192 + c] = hi; row[384 + c] = lo;
}

// fc2: LDS-staged tiny GEMM + transposed store
__launch_bounds__(192)
__global__ void k_fc2(const float* __restrict__ hfc, const float* __restrict__ fc2W,
                      const float* __restrict__ fc2b, float* __restrict__ out)
{
  __shared__ float w2S[12][193];
  __shared__ float hS[16][193];
  const int tid = threadIdx.x;
  const int q0 = blockIdx.x * 16;
  for (int idx = tid; idx < 12 * 192; idx += 192) {
    int o = idx / 192, k = idx - o * 192;
    w2S[o][k] = fc2W[idx];
  }
  for (int idx = tid; idx < 16 * 192; idx += 192) {
    int qq = idx / 192, k = idx - qq * 192;
    hS[qq][k] = hfc[(size_t)(q0 + qq) * 192 + k];
  }
  __syncthreads();
  const int qq = tid / 12, o = tid - qq * 12;
  float acc = fc2b[o];
#pragma unroll 8
  for (int k = 0; k < 192; k++) acc += hS[qq][k] * w2S[o][k];
  const int q = q0 + qq;
  const int b = q / 1000, node = q - b * 1000;
  out[(size_t)b * 12000 + o * 1000 + node] = acc;
}

// ============================================================
extern "C" void kernel_launch(void* const* d_in, const int* in_sizes, int n_in,
                              void* d_out, int out_size, void* d_ws, size_t ws_size,
                              hipStream_t stream)
{
  const float* x     = (const float*)d_in[0];
  const float* A     = (const float*)d_in[1];
  const float* FSP   = (const float*)d_in[2];
  const float* DSP   = (const float*)d_in[3];
  const float* E1    = (const float*)d_in[4];
  const float* E2    = (const float*)d_in[5];
  const float* fus_W = (const float*)d_in[6];
  const float* fus_b = (const float*)d_in[7];
  const float* fus_v = (const float*)d_in[8];
  const float* beta1 = (const float*)d_in[9];
  const float* beta2 = (const float*)d_in[10];
  const float* gcn_W1= (const float*)d_in[11];
  const float* gcn_b1= (const float*)d_in[12];
  const float* ln1g  = (const float*)d_in[13];
  const float* ln1b  = (const float*)d_in[14];
  const float* gcn_W2= (const float*)d_in[15];
  const float* gcn_b2= (const float*)d_in[16];
  const float* ln2g  = (const float*)d_in[17];
  const float* ln2b  = (const float*)d_in[18];
  const float* Wih0  = (const float*)d_in[19];
  const float* Whh0  = (const float*)d_in[20];
  const float* bih0  = (const float*)d_in[21];
  const float* bhh0  = (const float*)d_in[22];
  const float* Wih1  = (const float*)d_in[23];
  const float* Whh1  = (const float*)d_in[24];
  const float* bih1  = (const float*)d_in[25];
  const float* bhh1  = (const float*)d_in[26];
  const float* att_w = (const float*)d_in[27];
  const float* fc1W  = (const float*)d_in[28];
  const float* fc1b  = (const float*)d_in[29];
  const float* fc2W  = (const float*)d_in[30];
  const float* fc2b  = (const float*)d_in[31];
  float* out = (float*)d_out;

  char* w = (char*)d_ws;
  auto alloc = [&](size_t bytes) -> char* {
    char* p = w;
    w += (bytes + 255) & ~(size_t)255;
    return p;
  };

  float* consts  = (float*)alloc(8 * 4);
  float* scp     = (float*)alloc(3 * 4);
  float* alphap  = (float*)alloc(3 * 4);
  float* rowsums = (float*)alloc(3000 * 4);
  float* dinvp   = (float*)alloc(1000 * 4);
  u16*   Gbuf    = (u16*)alloc((size_t)3000000 * 2);
  u16*   Sbf     = (u16*)alloc((size_t)1024 * 1024 * 2);
  u16*   xbf     = (u16*)alloc((size_t)384000 * 2);
  u16*   fusWbf  = (u16*)alloc((size_t)32000 * 2);
  u16*   Wih0b   = (u16*)alloc((size_t)55296 * 2);
  u16*   Whh0b   = (u16*)alloc((size_t)110592 * 2);
  u16*   Wih1b   = (u16*)alloc((size_t)110592 * 2);
  u16*   Whh1b   = (u16*)alloc((size_t)110592 * 2);
  u16*   w1s     = (u16*)alloc((size_t)192 * 576 * 2);
  u16*   W2s     = (u16*)alloc((size_t)96 * 192 * 2);
  float4* cwpk   = (float4*)alloc((size_t)96 * 16);
  float* Pbuf    = (float*)alloc((size_t)96000 * 4);
  float* yt      = (float*)alloc((size_t)384000 * 4);
  u16*   h2t     = (u16*)alloc((size_t)36864 * 1024 * 2);  // 75.5 MB; states/FC alias later
  u16*   Gg      = (u16*)alloc((size_t)36864000 * 2);      // 73.7 MB
  float* Nv      = (float*)alloc((size_t)6144000 * 4);
  float* Mb0     = (float*)alloc((size_t)32000 * 4);
  float* Mb1     = (float*)alloc((size_t)32000 * 4);
  float* Lb0     = (float*)alloc((size_t)32000 * 4);
  float* Lb1     = (float*)alloc((size_t)32000 * 4);
  float* sc0     = (float*)alloc((size_t)32000 * 4);
  float* sc1     = (float*)alloc((size_t)32000 * 4);
  float* Mbuf[2] = { Mb0, Mb1 };
  float* Lbuf[2] = { Lb0, Lb1 };
  float* score[2]= { sc0, sc1 };

  u16* h0buf[2] = { h2t,                    h2t + (size_t)6144000 };
  u16* h1buf[2] = { h2t + (size_t)12288000, h2t + (size_t)18432000 };
  u16*   ctxs = h2t;
  float* hfc  = (float*)(h2t + (size_t)18432000);

  k_prep<<<3174, 256, 0, stream>>>(x, fus_W, Wih0, Whh0, Wih1, Whh1, gcn_W1, gcn_b1,
                                   gcn_W2, ln1g, ln1b,
                                   xbf, fusWbf, Wih0b, Whh0b, Wih1b, Whh1b, W2s, cwpk, consts);
  k_w1split<<<144, 256, 0, stream>>>(fc1W, w1s);
  k_zero<<<682, 256, 0, stream>>>(h2t, sc0, sc1);
  k_adjrow<<<1000, 256, 0, stream>>>(A, FSP, DSP, E1, E2, beta1, beta2, Gbuf, rowsums);
  gemm_nt<0><<<dim3(1, 24), 256, 0, stream>>>(Gbuf, 1000, fusWbf, 1000, Pbuf, 32, 3000, 32, 1000, nullptr);
  k_sc<<<3, 256, 0, stream>>>(Pbuf, fus_b, fus_v, scp);
  k_alpha<<<1, 256, 0, stream>>>(scp, rowsums, alphap, dinvp);
  k_shat<<<4000, 256, 0, stream>>>(Gbuf, alphap, dinvp, Sbf);
  gemm_nt<0><<<dim3(6, 8), 256, 0, stream>>>(Sbf, 1024, xbf, 1000, yt, 384, 1000, 384, 1000, nullptr);
  k_h2gemm<<<3000, 256, 0, stream>>>(yt, cwpk, W2s, consts, h2t);
  // Gg = LN2( S @ h2t^T + b2 )  (73.7 GFLOP, BK=64, fused LN2)
  k_bigemm<<<3072, 256, 0, stream>>>(Sbf, h2t, gcn_b2, ln2g, ln2b, Gg);

  // ---- GRU: persistent cooperative kernel (fallback: per-step launches) ----
  GruArgs ga;
  ga.Gg = Gg; ga.Wih0 = Wih0b; ga.Whh0 = Whh0b; ga.Wih1 = Wih1b; ga.Whh1 = Whh1b;
  ga.bih0 = bih0; ga.bhh0 = bhh0; ga.bih1 = bih1; ga.bhh1 = bhh1; ga.att_w = att_w;
  ga.h0a = h0buf[0]; ga.h0b = h0buf[1]; ga.h1a = h1buf[0]; ga.h1b = h1buf[1];
  ga.M0 = Mb0; ga.M1 = Mb1; ga.L0 = Lb0; ga.L1 = Lb1; ga.s0 = sc0; ga.s1 = sc1;
  ga.Nv = Nv;
  void* kargs[] = { (void*)&ga };
  hipError_t cerr = hipLaunchCooperativeKernel((void*)k_grup, dim3(1024), dim3(256),
                                               kargs, 0, stream);
  if (cerr != hipSuccess) {
    for (int t = 0; t < 12; ++t) {
      u16* h0in  = h0buf[t & 1];
      u16* h0out = h0buf[(t & 1) ^ 1];
      u16* h1in  = h1buf[t & 1];
      u16* h1out = h1buf[(t & 1) ^ 1];
      const int pm = (t == 0) ? 0 : (t == 1 ? 1 : 2);
      k_gru<96, false><<<dim3(6, 250), 256, 0, stream>>>(
          Gg + t * 96, 1152, Wih0b, h0in, Whh0b, bih0, bhh0, h0out,
          nullptr, nullptr, nullptr,
          h1in, score[(t + 1) & 1],
          Mbuf[(t + 1) & 1], Lbuf[(t + 1) & 1], Mbuf[t & 1], Lbuf[t & 1],
          Nv, t == 0, pm);
      k_gru<192, true><<<dim3(6, 250), 256, 0, stream>>>(
          h0out, 192, Wih1b, h1in, Whh1b, bih1, bhh1, h1out,
          att_w, score[t & 1], score[(t + 1) & 1],
          nullptr, nullptr, nullptr, nullptr, nullptr, nullptr, nullptr,
          t == 0, 0);
    }
  }
  // final pool tp=11
  k_pool<<<4000, 256, 0, stream>>>(h1buf[0], score[1], Mbuf[1], Lbuf[1], Lbuf[0], Nv);

  // FC head
  k_ctxsplit<<<24000, 256, 0, stream>>>(Nv, Lbuf[0], ctxs);
  gemm_nt<3><<<dim3(3, 250), 256, 0, stream>>>(ctxs, 576, w1s, 576, hfc, 192, 32000, 192, 576, fc1b);
  k_fc2<<<2000, 192, 0, stream>>>(hfc, fc2W, fc2b, out);
}

// Round 13
// 1447.914 us; speedup vs baseline: 3.2119x; 3.2119x over previous
//
#include <hip/hip_runtime.h>

typedef unsigned short u16;
typedef unsigned int u32;
typedef __attribute__((ext_vector_type(8))) short short8;   // 8 x bf16 (4 VGPRs)
typedef __attribute__((ext_vector_type(4))) float float4v;  // 4 x f32

#define DEV static __device__ __forceinline__

DEV float bf2f(u16 u) { u32 x = ((u32)u) << 16; float f; __builtin_memcpy(&f, &x, 4); return f; }
DEV u16 f2bf(float f) {
  u32 u; __builtin_memcpy(&u, &f, 4);
  u = (u + 0x7fffu + ((u >> 16) & 1u)) >> 16;
  return (u16)u;
}
DEV float sigm(float x) { return 1.f / (1.f + __expf(-x)); }

// async global->LDS, 16B per lane; LDS dest = wave-uniform base + lane*16
DEV void gl16(const u16* g, u16* l) {
  __builtin_amdgcn_global_load_lds(
      (const __attribute__((address_space(1))) void*)g,
      (__attribute__((address_space(3))) void*)l, 16, 0, 0);
}

// ============================================================
// Generic GEMM (small cases): C[M,N] = A[M,K](bf16) * B[N,K](bf16 "NK")
// OMODE: 0 = f32 row-major, 3 = f32 + bias + tanh-GELU epilogue (fc1)
// ============================================================
template <int OMODE>
__launch_bounds__(256)
__global__ void gemm_nt(const u16* __restrict__ A, int lda,
                        const u16* __restrict__ B, int ldb,
                        void* __restrict__ Cp, int ldc,
                        int M, int N, int K,
                        const float* __restrict__ bias)
{
  constexpr int PK = 40;
  __shared__ u16 As[128 * PK];
  __shared__ u16 Bs[64 * PK];

  const int tid  = threadIdx.x;
  const int m0   = blockIdx.y * 128;
  const int n0   = blockIdx.x * 64;
  const int wid  = tid >> 6;
  const int lane = tid & 63;
  const int l15  = lane & 15;
  const int quad = lane >> 4;
  const int wm   = (wid >> 1) * 64;
  const int wn   = (wid & 1) * 32;

  float4v acc[4][2];
  const float4v fz = {0.f, 0.f, 0.f, 0.f};
#pragma unroll
  for (int i = 0; i < 4; i++)
#pragma unroll
    for (int j = 0; j < 2; j++) acc[i][j] = fz;

  const int arow = tid >> 2;
  const int akc  = tid & 3;

  const int kt_count = (K + 31) / 32;
  for (int kt = 0; kt < kt_count; ++kt) {
    const int k0 = kt * 32 + akc * 8;
    const bool kok = (k0 < K);
    uint4 av0 = make_uint4(0, 0, 0, 0), av1 = av0, bv = av0;
    int ra = m0 + arow;
    if (kok && ra < M)        av0 = *(const uint4*)(A + (size_t)ra * lda + k0);
    if (kok && ra + 64 < M)   av1 = *(const uint4*)(A + (size_t)(ra + 64) * lda + k0);
    int rb = n0 + arow;
    if (kok && rb < N)        bv  = *(const uint4*)(B + (size_t)rb * ldb + k0);

    __syncthreads();
    *(uint4*)&As[arow * PK + akc * 8]        = av0;
    *(uint4*)&As[(arow + 64) * PK + akc * 8] = av1;
    *(uint4*)&Bs[arow * PK + akc * 8]        = bv;
    __syncthreads();

    short8 af[4], bfr[2];
#pragma unroll
    for (int i = 0; i < 4; i++)
      af[i] = *(const short8*)&As[(wm + i * 16 + l15) * PK + quad * 8];
#pragma unroll
    for (int j = 0; j < 2; j++)
      bfr[j] = *(const short8*)&Bs[(wn + j * 16 + l15) * PK + quad * 8];
#pragma unroll
    for (int i = 0; i < 4; i++)
#pragma unroll
      for (int j = 0; j < 2; j++)
        acc[i][j] = __builtin_amdgcn_mfma_f32_16x16x32_bf16(af[i], bfr[j], acc[i][j], 0, 0, 0);
  }

#pragma unroll
  for (int i = 0; i < 4; i++)
#pragma unroll
    for (int j = 0; j < 2; j++)
#pragma unroll
      for (int e = 0; e < 4; e++) {
        int r = m0 + wm + i * 16 + quad * 4 + e;
        int c = n0 + wn + j * 16 + l15;
        if (r < M && c < N) {
          float v = acc[i][j][e];
          if (OMODE == 0) ((float*)Cp)[(size_t)r * ldc + c] = v;
          else {
            float a = v + bias[c];
            float t = tanhf(0.7978845608028654f * (a + 0.044715f * a * a * a));
            ((float*)Cp)[(size_t)r * ldc + c] = 0.5f * a * (1.f + t);
          }
        }
      }
}

// ============================================================
// Big graph-conv GEMM + fused LN2: BK=64 (16 barrier iters), gl16,
// XOR swizzle, XCD swizzle; writes LN2'd bf16 in GRU g-layout.
// ============================================================
__launch_bounds__(256)
__global__ void k_bigemm(const u16* __restrict__ A,    // Sbf 1024x1024
                         const u16* __restrict__ B,    // h2t 36864x1024
                         const float* __restrict__ b2, const float* __restrict__ g2,
                         const float* __restrict__ be2,
                         u16* __restrict__ Gg)
{
  __shared__ u16 As[128 * 64];
  __shared__ u16 Bs[96 * 64];
  __shared__ float stats[2][2][128];

  const int tid  = threadIdx.x;
  const int bid  = blockIdx.x;
  const int xcd  = bid & 7;
  const int jj   = bid >> 3;
  const int m0   = (jj & 7) * 128;
  const int rt   = xcd + 8 * (jj >> 3);

  const int wid  = tid >> 6;
  const int lane = tid & 63;
  const int l15  = lane & 15;
  const int quad = lane >> 4;
  const int wm   = (wid >> 1) * 64;
  const int wn   = (wid & 1) * 48;
  const int wni  = wid & 1;

  const int srow8 = lane >> 3;
  const int sw8   = ((lane & 7) ^ srow8) * 8;

  const u16* abase = A + (size_t)(m0 + wid * 8 + srow8) * 1024 + sw8;
  const u16* bbase = B + (size_t)(rt * 96 + wid * 8 + srow8) * 1024 + sw8;

  float4v acc[4][3];
  const float4v fz = {0.f, 0.f, 0.f, 0.f};
#pragma unroll
  for (int i = 0; i < 4; i++)
#pragma unroll
    for (int j = 0; j < 3; j++) acc[i][j] = fz;

  for (int kt = 0; kt < 16; ++kt) {
    const int ko = kt * 64;
#pragma unroll
    for (int c = 0; c < 4; c++)
      gl16(abase + (size_t)c * 32 * 1024 + ko, &As[(c * 32 + wid * 8) * 64]);
#pragma unroll
    for (int c = 0; c < 3; c++)
      gl16(bbase + (size_t)c * 32 * 1024 + ko, &Bs[(c * 32 + wid * 8) * 64]);
    __syncthreads();
#pragma unroll
    for (int k32 = 0; k32 < 2; k32++) {
      const int swr = ((quad + 4 * k32) ^ (l15 & 7)) * 8;
      short8 af[4], bf[3];
#pragma unroll
      for (int i = 0; i < 4; i++)
        af[i] = *(const short8*)&As[(wm + i * 16 + l15) * 64 + swr];
#pragma unroll
      for (int j = 0; j < 3; j++)
        bf[j] = *(const short8*)&Bs[(wn + j * 16 + l15) * 64 + swr];
#pragma unroll
      for (int i = 0; i < 4; i++)
#pragma unroll
        for (int j = 0; j < 3; j++)
          acc[i][j] = __builtin_amdgcn_mfma_f32_16x16x32_bf16(af[i], bf[j], acc[i][j], 0, 0, 0);
    }
    __syncthreads();
  }

  // ---- fused LN2 epilogue ----
  float b2v[3], g2v[3], bev[3];
#pragma unroll
  for (int j = 0; j < 3; j++) {
    int c = wn + j * 16 + l15;
    b2v[j] = b2[c]; g2v[j] = g2[c]; bev[j] = be2[c];
  }
#pragma unroll
  for (int i = 0; i < 4; i++)
#pragma unroll
    for (int e = 0; e < 4; e++) {
      float s = 0.f, ss = 0.f;
#pragma unroll
      for (int j = 0; j < 3; j++) {
        float v = acc[i][j][e] + b2v[j];
        acc[i][j][e] = v;
        s += v; ss += v * v;
      }
      s += __shfl_xor(s, 1); ss += __shfl_xor(ss, 1);
      s += __shfl_xor(s, 2); ss += __shfl_xor(ss, 2);
      s += __shfl_xor(s, 4); ss += __shfl_xor(ss, 4);
      s += __shfl_xor(s, 8); ss += __shfl_xor(ss, 8);
      if (l15 == 0) {
        int rl = wm + i * 16 + quad * 4 + e;
        stats[wni][0][rl] = s;
        stats[wni][1][rl] = ss;
      }
    }
  __syncthreads();
#pragma unroll
  for (int i = 0; i < 4; i++)
#pragma unroll
    for (int e = 0; e < 4; e++) {
      int rl = wm + i * 16 + quad * 4 + e;
      int m = m0 + rl;
      if (m < 1000) {
        float ts  = stats[0][0][rl] + stats[1][0][rl];
        float tss = stats[0][1][rl] + stats[1][1][rl];
        float mean = ts * (1.f / 96.f);
        float var  = tss * (1.f / 96.f) - mean * mean;
        float isd  = rsqrtf(var + 1e-5f);
#pragma unroll
        for (int j = 0; j < 3; j++) {
          int c = wn + j * 16 + l15;
          Gg[(size_t)rt * 96000 + (size_t)m * 96 + c] =
              f2bf((acc[i][j][e] - mean) * isd * g2v[j] + bev[j]);
        }
      }
    }
}

// ============================================================
// Online-softmax pool fold for timestep tp (tile m0/c0 owns 128q x 32c).
// pm: 1 = init (tp==0), 2 = normal.
// ============================================================
DEV void pool_fold(int m0, int c0, int pm,
                   const u16* __restrict__ Hpool,
                   const float* __restrict__ score_rd,
                   const float* __restrict__ Mrd, const float* __restrict__ Lrd,
                   float* __restrict__ Mwr, float* __restrict__ Lwr,
                   float* __restrict__ Nvp)
{
  const int tid = threadIdx.x;
#pragma unroll
  for (int k = 0; k < 16; k++) {
    int idx = k * 256 + tid;
    int ql = idx >> 5, cl = idx & 31;
    int q = m0 + ql, c = c0 + cl;
    size_t nidx = (size_t)q * 192 + c;
    float s = score_rd[q];
    float hnew = bf2f(Hpool[nidx]);
    float so, wnf, prev;
    if (pm == 1) { so = 0.f; wnf = 1.f; prev = 0.f; }
    else {
      float Mo = Mrd[q];
      float Mn = fmaxf(Mo, s);
      so = __expf(Mo - Mn); wnf = __expf(s - Mn);
      prev = Nvp[nidx];
    }
    Nvp[nidx] = prev * so + wnf * hnew;
  }
  if (c0 == 0 && tid < 128) {
    int q = m0 + tid;
    float s = score_rd[q];
    if (pm == 1) { Mwr[q] = s; Lwr[q] = 1.f; }
    else {
      float Mo = Mrd[q], Mn = fmaxf(Mo, s);
      Mwr[q] = Mn;
      Lwr[q] = Lrd[q] * __expf(Mo - Mn) + __expf(s - Mn);
    }
  }
}

// ============================================================
// GRU tile device function. BM=128, 32 cols/gate.
// K=192 phases BK=64; K=96 X-phase BK=32. XOR-swizzled LDS.
// ============================================================
template <int KX, bool POOL>
DEV void gru_tile(u16* As, u16* Bs,
                  int m0, int c0,
                  const u16* __restrict__ Xin, int ldx,
                  const u16* __restrict__ Win,
                  const u16* __restrict__ Hin,
                  const u16* __restrict__ Whh,
                  const float* __restrict__ bih, const float* __restrict__ bhh,
                  u16* __restrict__ Hout,
                  const float* __restrict__ att_w,
                  float* __restrict__ score_acc,
                  const u16* __restrict__ Hpool,
                  const float* __restrict__ score_rd,
                  const float* __restrict__ Mrd, const float* __restrict__ Lrd,
                  float* __restrict__ Mwr, float* __restrict__ Lwr,
                  float* __restrict__ Nvp,
                  int t0, int pm)
{
  const int tid  = threadIdx.x;
  const int wid  = tid >> 6;
  const int lane = tid & 63;
  const int l15  = lane & 15;
  const int quad = lane >> 4;
  const int wm   = wid * 32;

  // ---- folded pool (layer0 part, timestep u-2) ----
  if (!POOL && pm)
    pool_fold(m0, c0, pm, Hpool, score_rd, Mrd, Lrd, Mwr, Lwr, Nvp);

  const int srow8 = lane >> 3;
  const int sw8   = ((lane & 7) ^ srow8) * 8;
  const int srow4 = lane >> 2;
  const int sw4   = ((lane & 3) ^ ((lane >> 3) & 3)) * 8;

  float4v aR[2][2], aZ[2][2], aXN[2][2], aHN[2][2];
  const float4v fz = {0.f, 0.f, 0.f, 0.f};
#pragma unroll
  for (int i = 0; i < 2; i++)
#pragma unroll
    for (int j = 0; j < 2; j++) { aR[i][j] = fz; aZ[i][j] = fz; aXN[i][j] = fz; aHN[i][j] = fz; }

  // ---- phase X ----
  if (KX == 96) {
    const u16* ax0 = Xin + (size_t)(m0 + wid * 16 + srow4) * ldx + sw4;
    const u16* ax1 = Xin + (size_t)(m0 + 64 + wid * 16 + srow4) * ldx + sw4;
    const int b0 = wid * 16 + srow4;
    const u16* bx0 = Win + (size_t)((b0 >> 5) * 192 + c0 + (b0 & 31)) * 96 + sw4;
    const int b1 = 64 + wid * 16 + srow4;
    const u16* bx1 = Win + (size_t)(384 + c0 + (b1 & 31)) * 96 + sw4;
    u16* asl0 = &As[(wid * 16) * 32];
    u16* asl1 = &As[(64 + wid * 16) * 32];
    u16* bsl0 = &Bs[(wid * 16) * 32];
    u16* bsl1 = &Bs[(64 + wid * 16) * 32];
    const int swa = (quad ^ ((l15 >> 1) & 3)) * 8;
#pragma unroll
    for (int kt = 0; kt < 3; ++kt) {
      const int ko = kt * 32;
      gl16(ax0 + ko, asl0); gl16(ax1 + ko, asl1);
      gl16(bx0 + ko, bsl0);
      if (wid < 2) gl16(bx1 + ko, bsl1);
      __syncthreads();
      short8 af[2], bR[2], bZ[2], bN[2];
#pragma unroll
      for (int i = 0; i < 2; i++)
        af[i] = *(const short8*)&As[(wm + i * 16 + l15) * 32 + swa];
#pragma unroll
      for (int j = 0; j < 2; j++) {
        bR[j] = *(const short8*)&Bs[(j * 16 + l15) * 32 + swa];
        bZ[j] = *(const short8*)&Bs[(32 + j * 16 + l15) * 32 + swa];
        bN[j] = *(const short8*)&Bs[(64 + j * 16 + l15) * 32 + swa];
      }
#pragma unroll
      for (int i = 0; i < 2; i++)
#pragma unroll
        for (int j = 0; j < 2; j++) {
          aR[i][j]  = __builtin_amdgcn_mfma_f32_16x16x32_bf16(af[i], bR[j], aR[i][j], 0, 0, 0);
          aZ[i][j]  = __builtin_amdgcn_mfma_f32_16x16x32_bf16(af[i], bZ[j], aZ[i][j], 0, 0, 0);
          aXN[i][j] = __builtin_amdgcn_mfma_f32_16x16x32_bf16(af[i], bN[j], aXN[i][j], 0, 0, 0);
        }
      __syncthreads();
    }
  } else {
    const u16* abase = Xin + (size_t)(m0 + wid * 8 + srow8) * 192 + sw8;
    const u16* bbase = Win + (size_t)(c0 + wid * 8 + srow8) * 192 + sw8;
#pragma unroll
    for (int kt = 0; kt < 3; ++kt) {
      const int ko = kt * 64;
#pragma unroll
      for (int c = 0; c < 4; c++)
        gl16(abase + (size_t)c * 32 * 192 + ko, &As[(c * 32 + wid * 8) * 64]);
#pragma unroll
      for (int c = 0; c < 3; c++)
        gl16(bbase + (size_t)c * 192 * 192 + ko, &Bs[(c * 32 + wid * 8) * 64]);
      __syncthreads();
#pragma unroll
      for (int k32 = 0; k32 < 2; k32++) {
        const int swr = ((quad + 4 * k32) ^ (l15 & 7)) * 8;
        short8 af[2], bR[2], bZ[2], bN[2];
#pragma unroll
        for (int i = 0; i < 2; i++)
          af[i] = *(const short8*)&As[(wm + i * 16 + l15) * 64 + swr];
#pragma unroll
        for (int j = 0; j < 2; j++) {
          bR[j] = *(const short8*)&Bs[(j * 16 + l15) * 64 + swr];
          bZ[j] = *(const short8*)&Bs[(32 + j * 16 + l15) * 64 + swr];
          bN[j] = *(const short8*)&Bs[(64 + j * 16 + l15) * 64 + swr];
        }
#pragma unroll
        for (int i = 0; i < 2; i++)
#pragma unroll
          for (int j = 0; j < 2; j++) {
            aR[i][j]  = __builtin_amdgcn_mfma_f32_16x16x32_bf16(af[i], bR[j], aR[i][j], 0, 0, 0);
            aZ[i][j]  = __builtin_amdgcn_mfma_f32_16x16x32_bf16(af[i], bZ[j], aZ[i][j], 0, 0, 0);
            aXN[i][j] = __builtin_amdgcn_mfma_f32_16x16x32_bf16(af[i], bN[j], aXN[i][j], 0, 0, 0);
          }
      }
      __syncthreads();
    }
  }
  // ---- phase H: K=192, BK=64 x 3 ----
  if (!t0) {
    const u16* abase = Hin + (size_t)(m0 + wid * 8 + srow8) * 192 + sw8;
    const u16* bbase = Whh + (size_t)(c0 + wid * 8 + srow8) * 192 + sw8;
#pragma unroll
    for (int kt = 0; kt < 3; ++kt) {
      const int ko = kt * 64;
#pragma unroll
      for (int c = 0; c < 4; c++)
        gl16(abase + (size_t)c * 32 * 192 + ko, &As[(c * 32 + wid * 8) * 64]);
#pragma unroll
      for (int c = 0; c < 3; c++)
        gl16(bbase + (size_t)c * 192 * 192 + ko, &Bs[(c * 32 + wid * 8) * 64]);
      __syncthreads();
#pragma unroll
      for (int k32 = 0; k32 < 2; k32++) {
        const int swr = ((quad + 4 * k32) ^ (l15 & 7)) * 8;
        short8 af[2], bR[2], bZ[2], bN[2];
#pragma unroll
        for (int i = 0; i < 2; i++)
          af[i] = *(const short8*)&As[(wm + i * 16 + l15) * 64 + swr];
#pragma unroll
        for (int j = 0; j < 2; j++) {
          bR[j] = *(const short8*)&Bs[(j * 16 + l15) * 64 + swr];
          bZ[j] = *(const short8*)&Bs[(32 + j * 16 + l15) * 64 + swr];
          bN[j] = *(const short8*)&Bs[(64 + j * 16 + l15) * 64 + swr];
        }
#pragma unroll
        for (int i = 0; i < 2; i++)
#pragma unroll
          for (int j = 0; j < 2; j++) {
            aR[i][j]  = __builtin_amdgcn_mfma_f32_16x16x32_bf16(af[i], bR[j], aR[i][j], 0, 0, 0);
            aZ[i][j]  = __builtin_amdgcn_mfma_f32_16x16x32_bf16(af[i], bZ[j], aZ[i][j], 0, 0, 0);
            aHN[i][j] = __builtin_amdgcn_mfma_f32_16x16x32_bf16(af[i], bN[j], aHN[i][j], 0, 0, 0);
          }
      }
      __syncthreads();
    }
  }

  // ---- epilogue: gates + state write (+ pooling partials) ----
  float ps[2][4];
  if (POOL) {
#pragma unroll
    for (int i = 0; i < 2; i++)
#pragma unroll
      for (int e = 0; e < 4; e++) ps[i][e] = 0.f;
  }
#pragma unroll
  for (int j = 0; j < 2; ++j) {
    const int c = c0 + j * 16 + l15;
    const float brz = bih[c] + bhh[c];
    const float bzz = bih[192 + c] + bhh[192 + c];
    const float bxn = bih[384 + c];
    const float bhn = bhh[384 + c];
    const float aw  = POOL ? att_w[c] : 0.f;
#pragma unroll
    for (int i = 0; i < 2; ++i)
#pragma unroll
      for (int e = 0; e < 4; ++e) {
        const int row = m0 + wm + i * 16 + quad * 4 + e;
        float rg  = sigm(aR[i][j][e] + brz);
        float zg  = sigm(aZ[i][j][e] + bzz);
        float hnv = bhn + (t0 ? 0.f : aHN[i][j][e]);
        float ng  = tanhf(aXN[i][j][e] + bxn + rg * hnv);
        float hold = t0 ? 0.f : bf2f(Hin[(size_t)row * 192 + c]);
        float hnew = (1.f - zg) * ng + zg * hold;
        Hout[(size_t)row * 192 + c] = f2bf(hnew);
        if (POOL) ps[i][e] += hnew * aw;
      }
  }
  if (POOL) {
#pragma unroll
    for (int i = 0; i < 2; ++i)
#pragma unroll
      for (int e = 0; e < 4; ++e) {
        float v = ps[i][e];
        v += __shfl_xor(v, 1); v += __shfl_xor(v, 2);
        v += __shfl_xor(v, 4); v += __shfl_xor(v, 8);
        if (l15 == 0) atomicAdd(&score_acc[m0 + wm + i * 16 + quad * 4 + e], v);
      }
  }
}

// ============================================================
// Merged GRU launch u (0..12): x<6 -> layer0(step u) + fold(u-2),
// x>=6 -> layer1(step u-1). At u=12 the layer0 branch is fold-only (tp=10).
// h1/score triple-buffered (mod 3); M/L double-buffered (tp parity).
// ============================================================
struct GruArgs {
  const u16 *Gg, *Wih0, *Whh0, *Wih1, *Whh1;
  const float *bih0, *bhh0, *bih1, *bhh1, *att_w;
  u16 *h0[2];
  u16 *h1[3];
  float *M[2], *L[2], *s[3];
  float* Nv;
};

__launch_bounds__(256)
__global__ void k_gru2(GruArgs a, int u)
{
  __shared__ u16 As[128 * 64];
  __shared__ u16 Bs[96 * 64];
  const int m0 = blockIdx.y * 128;

  if (blockIdx.x < 6) {
    const int c0 = blockIdx.x * 32;
    const int pm = (u < 2) ? 0 : (u == 2 ? 1 : 2);
    if (u > 11) {
      // fold-only for tp = u-2 = 10 (the GEMM part is done; layer1(11) runs concurrently)
      if (pm)
        pool_fold(m0, c0, pm, a.h1[(u + 1) % 3], a.s[(u + 1) % 3],
                  a.M[(u + 1) & 1], a.L[(u + 1) & 1], a.M[u & 1], a.L[u & 1], a.Nv);
      return;
    }
    // zero score[u%3] (accumulated at launch u+1, folded at launch u+3)
    if (c0 == 0 && threadIdx.x < 128) a.s[u % 3][m0 + threadIdx.x] = 0.f;
    gru_tile<96, false>(As, Bs, m0, c0,
        a.Gg + u * 96, 1152, a.Wih0, a.h0[u & 1], a.Whh0, a.bih0, a.bhh0, a.h0[(u & 1) ^ 1],
        nullptr, nullptr,
        a.h1[(u + 1) % 3], a.s[(u + 1) % 3],           // tp=u-2 state & score
        a.M[(u + 1) & 1], a.L[(u + 1) & 1],            // post-(tp-1) state
        a.M[u & 1], a.L[u & 1],                        // post-tp state
        a.Nv, u == 0, pm);
  } else {
    if (u < 1) return;
    const int t = u - 1;
    const int c0 = (blockIdx.x - 6) * 32;
    gru_tile<192, true>(As, Bs, m0, c0,
        a.h0[u & 1], 192, a.Wih1, a.h1[(u + 1) % 3], a.Whh1, a.bih1, a.bhh1, a.h1[t % 3],
        a.att_w, a.s[t % 3],
        nullptr, nullptr, nullptr, nullptr, nullptr, nullptr, nullptr,
        t == 0, 0);
  }
}

// final pool (tp = 11): 8 q per 256-thread block
__launch_bounds__(256)
__global__ void k_pool(const u16* __restrict__ H, const float* __restrict__ score_rd,
                       const float* __restrict__ Mrd, const float* __restrict__ Lrd,
                       float* __restrict__ Lwr, float* __restrict__ Nv)
{
  const int base = blockIdx.x * 1536;
  const int tid  = threadIdx.x;
#pragma unroll
  for (int k = 0; k < 6; k++) {
    const int idx = base + tid + k * 256;
    const int q = idx / 192;
    const float s = score_rd[q];
    const float Mo = Mrd[q];
    const float Mn = fmaxf(Mo, s);
    const float so = __expf(Mo - Mn);
    const float wn = __expf(s - Mn);
    Nv[idx] = Nv[idx] * so + wn * bf2f(H[idx]);
  }
  if (tid < 8) {
    const int q = blockIdx.x * 8 + tid;
    const float s = score_rd[q];
    const float Mo = Mrd[q];
    const float Mn = fmaxf(Mo, s);
    Lwr[q] = Lrd[q] * __expf(Mo - Mn) + __expf(s - Mn);
  }
}

// ============================================================
// H2 GEMM: h2t[(r*96+c2)*1024+n] = Hln @ W2 (analytic LN1 in A-staging)
// ============================================================
__launch_bounds__(256)
__global__ void k_h2gemm(const float* __restrict__ yt, const float4* __restrict__ cwpk,
                         const u16* __restrict__ W2s, const float* __restrict__ consts,
                         u16* __restrict__ h2t)
{
  constexpr int PK = 40;
  __shared__ u16 As[128 * PK];
  __shared__ u16 Bs[96 * PK];
  __shared__ u16 Ts[96 * 136];

  const int tid  = threadIdx.x;
  const int m0   = blockIdx.x * 128;
  const int wid  = tid >> 6;
  const int lane = tid & 63;
  const int l15  = lane & 15;
  const int quad = lane >> 4;
  const int wm   = (wid >> 1) * 64;
  const int wn   = (wid & 1) * 48;

  const float P = consts[0], Q = consts[1], VW = consts[2], CWB = consts[3], VB = consts[4];

  const int arow = tid >> 2;
  const int akc  = tid & 3;

  float yv[2], mu[2], iv[2];
#pragma unroll
  for (int rr = 0; rr < 2; rr++) {
    int i = m0 + arow + rr * 64;
    int r = i / 1000, n = i - r * 1000;
    float y = yt[n * 384 + r];
    yv[rr] = y;
    mu[rr] = y * P + Q;
    iv[rr] = rsqrtf(y * y * VW + 2.f * y * CWB + VB + 1e-5f);
  }

  float4v acc[4][3];
  const float4v fz = {0.f, 0.f, 0.f, 0.f};
#pragma unroll
  for (int i = 0; i < 4; i++)
#pragma unroll
    for (int j = 0; j < 3; j++) acc[i][j] = fz;

  uint4 asave[2][3];
  const bool has2 = (arow < 32);

  for (int kt = 0; kt < 6; ++kt) {
    const int k0 = kt * 32 + akc * 8;
    uint4 av[2];
    if (kt < 3) {
#pragma unroll
      for (int rr = 0; rr < 2; rr++) {
        u16 hb[8];
#pragma unroll
        for (int e = 0; e < 8; e++) {
          float4 cw = cwpk[k0 + e];
          float t = yv[rr] * cw.x + cw.y - mu[rr];
          float h = fmaxf(t * iv[rr] * cw.z + cw.w, 0.f);
          hb[e] = f2bf(h);
        }
        __builtin_memcpy(&av[rr], hb, 16);
        asave[rr][kt] = av[rr];
      }
    } else {
      av[0] = asave[0][kt - 3];
      av[1] = asave[1][kt - 3];
    }
    uint4 bv0 = *(const uint4*)(W2s + (size_t)arow * 192 + k0);
    uint4 bv1 = make_uint4(0, 0, 0, 0);
    if (has2) bv1 = *(const uint4*)(W2s + (size_t)(arow + 64) * 192 + k0);

    __syncthreads();
    *(uint4*)&As[arow * PK + akc * 8]        = av[0];
    *(uint4*)&As[(arow + 64) * PK + akc * 8] = av[1];
    *(uint4*)&Bs[arow * PK + akc * 8]        = bv0;
    if (has2) *(uint4*)&Bs[(arow + 64) * PK + akc * 8] = bv1;
    __syncthreads();

    short8 af[4], bfr[3];
#pragma unroll
    for (int i = 0; i < 4; i++)
      af[i] = *(const short8*)&As[(wm + i * 16 + l15) * PK + quad * 8];
#pragma unroll
    for (int j = 0; j < 3; j++)
      bfr[j] = *(const short8*)&Bs[(wn + j * 16 + l15) * PK + quad * 8];
#pragma unroll
    for (int i = 0; i < 4; i++)
#pragma unroll
      for (int j = 0; j < 3; j++)
        acc[i][j] = __builtin_amdgcn_mfma_f32_16x16x32_bf16(af[i], bfr[j], acc[i][j], 0, 0, 0);
  }

#pragma unroll
  for (int i = 0; i < 4; i++)
#pragma unroll
    for (int j = 0; j < 3; j++)
#pragma unroll
      for (int e = 0; e < 4; e++) {
        int rowl = wm + i * 16 + quad * 4 + e;
        int c2   = wn + j * 16 + l15;
        Ts[c2 * 136 + rowl] = f2bf(acc[i][j][e]);
      }
  __syncthreads();
#pragma unroll
  for (int u = tid; u < 1536; u += 256) {
    int c2 = u >> 4, ch = u & 15;
    int iidx0 = m0 + ch * 8;
    int r = iidx0 / 1000, n0 = iidx0 - r * 1000;
    *(uint4*)(h2t + (size_t)(r * 96 + c2) * 1024 + n0) = *(const uint4*)&Ts[c2 * 136 + ch * 8];
  }
}

// ============================================================
// prep: f32 -> bf16 conversions + W1/b1 moment stats + W2 split + cw pack
// ============================================================
__launch_bounds__(256)
__global__ void k_prep(const float* x, const float* fus_W,
                       const float* Wih0, const float* Whh0,
                       const float* Wih1, const float* Whh1,
                       const float* gcn_W1, const float* gcn_b1,
                       const float* gcn_W2, const float* ln1g, const float* ln1b,
                       u16* xbf, u16* fusWbf, u16* Wih0b, u16* Whh0b, u16* Wih1b, u16* Whh1b,
                       u16* W2s, float4* cwpk, float* consts)
{
  long o = (long)blockIdx.x * 256 + threadIdx.x;
  if (o < 384000) xbf[o] = f2bf(x[o]);
  else if ((o -= 384000) < 32000) fusWbf[o] = f2bf(fus_W[o]);
  else if ((o -= 32000) < 55296)  Wih0b[o] = f2bf(Wih0[o]);
  else if ((o -= 55296) < 110592) Whh0b[o] = f2bf(Whh0[o]);
  else if ((o -= 110592) < 110592) Wih1b[o] = f2bf(Wih1[o]);
  else if ((o -= 110592) < 110592) Whh1b[o] = f2bf(Whh1[o]);
  else if ((o -= 110592) < 9216) {
    int c2 = (int)o / 96, c = (int)o - c2 * 96;
    float wv = gcn_W2[c * 96 + c2];
    u16 hi = f2bf(wv);
    u16 lo = f2bf(wv - bf2f(hi));
    W2s[c2 * 192 + c] = hi;
    W2s[c2 * 192 + 96 + c] = lo;
  }
  else if ((o -= 9216) < 96) {
    int c = (int)o;
    float4 cw;
    cw.x = gcn_W1[c]; cw.y = gcn_b1[c]; cw.z = ln1g[c]; cw.w = ln1b[c];
    cwpk[c] = cw;
  }
  if (blockIdx.x == 0 && threadIdx.x == 0) {
    float sw = 0, sb = 0, sww = 0, swb = 0, sbb = 0;
    for (int c = 0; c < 96; c++) {
      float wv = gcn_W1[c], b = gcn_b1[c];
      sw += wv; sb += b; sww += wv * wv; swb += wv * b; sbb += b * b;
    }
    float P = sw / 96.f, Q = sb / 96.f;
    consts[0] = P; consts[1] = Q;
    consts[2] = sww / 96.f - P * P;
    consts[3] = swb / 96.f - P * Q;
    consts[4] = sbb / 96.f - Q * Q;
  }
}

// zero-fill: h2t K-pad columns (1000..1023) + three score buffers
__launch_bounds__(256)
__global__ void k_zero(u16* __restrict__ h2t, float* __restrict__ s0,
                       float* __restrict__ s1, float* __restrict__ s2)
{
  int idx = blockIdx.x * 256 + threadIdx.x;
  if (idx < 110592) {
    int row = idx / 3, p = idx - row * 3;
    *(uint4*)(h2t + (size_t)row * 1024 + 1000 + p * 8) = make_uint4(0, 0, 0, 0);
  } else if ((idx -= 110592) < 32000) {
    s0[idx] = 0.f;
  } else if ((idx -= 32000) < 32000) {
    s1[idx] = 0.f;
  } else if ((idx -= 32000) < 32000) {
    s2[idx] = 0.f;
  }
}

// fc1W (192x192 f32) -> split-bf16 B' (192 x 576): [wh | wl | wh]
__launch_bounds__(256)
__global__ void k_w1split(const float* __restrict__ fc1W, u16* __restrict__ w1s)
{
  int idx = blockIdx.x * 256 + threadIdx.x;
  if (idx >= 192 * 192) return;
  int n = idx / 192, k = idx - n * 192;
  float w = fc1W[idx];
  u16 hi = f2bf(w);
  u16 lo = f2bf(w - bf2f(hi));
  w1s[(size_t)n * 576 + k]       = hi;
  w1s[(size_t)n * 576 + 192 + k] = lo;
  w1s[(size_t)n * 576 + 384 + k] = hi;
}

// ============================================================
// per-row: Aadp softmax row + the 3 candidate graphs (bf16) + row sums
// ============================================================
__launch_bounds__(256)
__global__ void k_adjrow(const float* __restrict__ A, const float* __restrict__ FSP,
                         const float* __restrict__ DSP, const float* __restrict__ E1,
                         const float* __restrict__ E2,
                         const float* beta1, const float* beta2,
                         u16* __restrict__ G, float* __restrict__ rowsums)
{
  __shared__ float z[1000];
  __shared__ float red[256];
  const int n = blockIdx.x, tid = threadIdx.x;

  float e1r[10];
#pragma unroll
  for (int d = 0; d < 10; d++) e1r[d] = E1[n * 10 + d];

  float lmax = -1e30f;
  for (int m = tid; m < 1000; m += 256) {
    float s = 0;
#pragma unroll
    for (int d = 0; d < 10; d++) s += e1r[d] * E2[m * 10 + d];
    s = fmaxf(s, 0.f);
    z[m] = s;
    lmax = fmaxf(lmax, s);
  }
  red[tid] = lmax; __syncthreads();
  for (int st = 128; st > 0; st >>= 1) { if (tid < st) red[tid] = fmaxf(red[tid], red[tid + st]); __syncthreads(); }
  const float mx = red[0]; __syncthreads();

  float lsum = 0;
  for (int m = tid; m < 1000; m += 256) { float e = __expf(z[m] - mx); z[m] = e; lsum += e; }
  red[tid] = lsum; __syncthreads();
  for (int st = 128; st > 0; st >>= 1) { if (tid < st) red[tid] += red[tid + st]; __syncthreads(); }
  const float inv = 1.f / red[0]; __syncthreads();

  const float w1 = sigm(beta1[0]);
  const float w2 = sigm(beta2[0]);
  float s0 = 0, s1 = 0, s2 = 0;
  for (int m = tid; m < 1000; m += 256) {
    float aadp = z[m] * inv;
    float a = A[n * 1000 + m], f = FSP[n * 1000 + m], dd = DSP[n * 1000 + m];
    float g0 = 0.5f * a + 0.5f * aadp;
    float g1 = w1 * a + (1.f - w1) * f;
    float g2 = w2 * a + (1.f - w2) * dd;
    G[0 * 1000000 + n * 1000 + m] = f2bf(g0);
    G[1 * 1000000 + n * 1000 + m] = f2bf(g1);
    G[2 * 1000000 + n * 1000 + m] = f2bf(g2);
    s0 += g0; s1 += g1; s2 += g2;
  }
  red[tid] = s0; __syncthreads();
  for (int st = 128; st > 0; st >>= 1) { if (tid < st) red[tid] += red[tid + st]; __syncthreads(); }
  if (tid == 0) rowsums[n] = red[0];
  __syncthreads();
  red[tid] = s1; __syncthreads();
  for (int st = 128; st > 0; st >>= 1) { if (tid < st) red[tid] += red[tid + st]; __syncthreads(); }
  if (tid == 0) rowsums[1000 + n] = red[0];
  __syncthreads();
  red[tid] = s2; __syncthreads();
  for (int st = 128; st > 0; st >>= 1) { if (tid < st) red[tid] += red[tid + st]; __syncthreads(); }
  if (tid == 0) rowsums[2000 + n] = red[0];
}

// sc[k] = mean_n( sum_a tanh(P[k,n,a]+fus_b[a]) * fus_v[a] )
__launch_bounds__(256)
__global__ void k_sc(const float* __restrict__ P, const float* fus_b, const float* fus_v, float* sc)
{
  __shared__ float red[256];
  const int k = blockIdx.x, tid = threadIdx.x;
  float local = 0;
  for (int n = tid; n < 1000; n += 256) {
    const float* p = P + (size_t)(k * 1000 + n) * 32;
    float s = 0;
#pragma unroll
    for (int a = 0; a < 32; a++) s += tanhf(p[a] + fus_b[a]) * fus_v[a];
    local += s;
  }
  red[tid] = local; __syncthreads();
  for (int st = 128; st > 0; st >>= 1) { if (tid < st) red[tid] += red[tid + st]; __syncthreads(); }
  if (tid == 0) sc[k] = red[0] * (1.f / 1000.f);
}

__launch_bounds__(256)
__global__ void k_alpha(const float* sc, const float* rowsums, float* alpha_out, float* dinv)
{
  __shared__ float al[3];
  const int tid = threadIdx.x;
  if (tid == 0) {
    float m = fmaxf(sc[0], fmaxf(sc[1], sc[2]));
    float e0 = __expf(sc[0] - m), e1 = __expf(sc[1] - m), e2 = __expf(sc[2] - m);
    float inv = 1.f / (e0 + e1 + e2);
    al[0] = e0 * inv; al[1] = e1 * inv; al[2] = e2 * inv;
    alpha_out[0] = al[0]; alpha_out[1] = al[1]; alpha_out[2] = al[2];
  }
  __syncthreads();
  const float a0 = al[0], a1 = al[1], a2 = al[2];
  for (int n = tid; n < 1000; n += 256) {
    float d = a0 * rowsums[n] + a1 * rowsums[1000 + n] + a2 * rowsums[2000 + n] + 1.0f;
    dinv[n] = rsqrtf(fmaxf(d, 1e-12f));
  }
}

// S_hat -> Sbf with 1024 K-pad stride (pad cols zeroed)
__launch_bounds__(256)
__global__ void k_shat(const u16* __restrict__ G, const float* alpha, const float* dinv,
                       u16* __restrict__ S)
{
  int idx = blockIdx.x * 256 + threadIdx.x;
  if (idx >= 1024000) return;
  int i = idx >> 10, j = idx & 1023;
  u16 val = 0;
  if (j < 1000) {
    const float a0 = alpha[0], a1 = alpha[1], a2 = alpha[2];
    int g = i * 1000 + j;
    float mg = a0 * bf2f(G[g]) + a1 * bf2f(G[1000000 + g]) + a2 * bf2f(G[2000000 + g]);
    if (i == j) mg += 1.0f;
    val = f2bf(mg * dinv[i] * dinv[j]);
  }
  S[(size_t)i * 1024 + j] = val;
}

// ctx = Nv/L, split to hi/lo bf16, pack A' rows [ch | ch | cl] (K=576)
__launch_bounds__(256)
__global__ void k_ctxsplit(const float* __restrict__ Nv, const float* __restrict__ Lbuf,
                           u16* __restrict__ ctxs)
{
  const int i = blockIdx.x * 256 + threadIdx.x;
  if (i >= 32000 * 192) return;
  const int q = i / 192, c = i - q * 192;
  float v = Nv[i] / Lbuf[q];
  u16 hi = f2bf(v);
  u16 lo = f2bf(v - bf2f(hi));
  u16* row = ctxs + (size_t)q * 576;
  row[c] = hi; row[192 + c] = hi; row[384 + c] = lo;
}

// fc2: LDS-staged tiny GEMM + transposed store
__launch_bounds__(192)
__global__ void k_fc2(const float* __restrict__ hfc, const float* __restrict__ fc2W,
                      const float* __restrict__ fc2b, float* __restrict__ out)
{
  __shared__ float w2S[12][193];
  __shared__ float hS[16][193];
  const int tid = threadIdx.x;
  const int q0 = blockIdx.x * 16;
  for (int idx = tid; idx < 12 * 192; idx += 192) {
    int o = idx / 192, k = idx - o * 192;
    w2S[o][k] = fc2W[idx];
  }
  for (int idx = tid; idx < 16 * 192; idx += 192) {
    int qq = idx / 192, k = idx - qq * 192;
    hS[qq][k] = hfc[(size_t)(q0 + qq) * 192 + k];
  }
  __syncthreads();
  const int qq = tid / 12, o = tid - qq * 12;
  float acc = fc2b[o];
#pragma unroll 8
  for (int k = 0; k < 192; k++) acc += hS[qq][k] * w2S[o][k];
  const int q = q0 + qq;
  const int b = q / 1000, node = q - b * 1000;
  out[(size_t)b * 12000 + o * 1000 + node] = acc;
}

// ============================================================
extern "C" void kernel_launch(void* const* d_in, const int* in_sizes, int n_in,
                              void* d_out, int out_size, void* d_ws, size_t ws_size,
                              hipStream_t stream)
{
  const float* x     = (const float*)d_in[0];
  const float* A     = (const float*)d_in[1];
  const float* FSP   = (const float*)d_in[2];
  const float* DSP   = (const float*)d_in[3];
  const float* E1    = (const float*)d_in[4];
  const float* E2    = (const float*)d_in[5];
  const float* fus_W = (const float*)d_in[6];
  const float* fus_b = (const float*)d_in[7];
  const float* fus_v = (const float*)d_in[8];
  const float* beta1 = (const float*)d_in[9];
  const float* beta2 = (const float*)d_in[10];
  const float* gcn_W1= (const float*)d_in[11];
  const float* gcn_b1= (const float*)d_in[12];
  const float* ln1g  = (const float*)d_in[13];
  const float* ln1b  = (const float*)d_in[14];
  const float* gcn_W2= (const float*)d_in[15];
  const float* gcn_b2= (const float*)d_in[16];
  const float* ln2g  = (const float*)d_in[17];
  const float* ln2b  = (const float*)d_in[18];
  const float* Wih0  = (const float*)d_in[19];
  const float* Whh0  = (const float*)d_in[20];
  const float* bih0  = (const float*)d_in[21];
  const float* bhh0  = (const float*)d_in[22];
  const float* Wih1  = (const float*)d_in[23];
  const float* Whh1  = (const float*)d_in[24];
  const float* bih1  = (const float*)d_in[25];
  const float* bhh1  = (const float*)d_in[26];
  const float* att_w = (const float*)d_in[27];
  const float* fc1W  = (const float*)d_in[28];
  const float* fc1b  = (const float*)d_in[29];
  const float* fc2W  = (const float*)d_in[30];
  const float* fc2b  = (const float*)d_in[31];
  float* out = (float*)d_out;

  char* w = (char*)d_ws;
  auto alloc = [&](size_t bytes) -> char* {
    char* p = w;
    w += (bytes + 255) & ~(size_t)255;
    return p;
  };

  float* consts  = (float*)alloc(8 * 4);
  float* scp     = (float*)alloc(3 * 4);
  float* alphap  = (float*)alloc(3 * 4);
  float* rowsums = (float*)alloc(3000 * 4);
  float* dinvp   = (float*)alloc(1000 * 4);
  u16*   Gbuf    = (u16*)alloc((size_t)3000000 * 2);
  u16*   Sbf     = (u16*)alloc((size_t)1024 * 1024 * 2);
  u16*   xbf     = (u16*)alloc((size_t)384000 * 2);
  u16*   fusWbf  = (u16*)alloc((size_t)32000 * 2);
  u16*   Wih0b   = (u16*)alloc((size_t)55296 * 2);
  u16*   Whh0b   = (u16*)alloc((size_t)110592 * 2);
  u16*   Wih1b   = (u16*)alloc((size_t)110592 * 2);
  u16*   Whh1b   = (u16*)alloc((size_t)110592 * 2);
  u16*   w1s     = (u16*)alloc((size_t)192 * 576 * 2);
  u16*   W2s     = (u16*)alloc((size_t)96 * 192 * 2);
  float4* cwpk   = (float4*)alloc((size_t)96 * 16);
  float* Pbuf    = (float*)alloc((size_t)96000 * 4);
  float* yt      = (float*)alloc((size_t)384000 * 4);
  u16*   h2t     = (u16*)alloc((size_t)36864 * 1024 * 2);  // 75.5 MB; states/FC alias later
  u16*   Gg      = (u16*)alloc((size_t)36864000 * 2);      // 73.7 MB
  float* Nv      = (float*)alloc((size_t)6144000 * 4);
  float* Mb0     = (float*)alloc((size_t)32000 * 4);
  float* Mb1     = (float*)alloc((size_t)32000 * 4);
  float* Lb0     = (float*)alloc((size_t)32000 * 4);
  float* Lb1     = (float*)alloc((size_t)32000 * 4);
  float* sc0     = (float*)alloc((size_t)32000 * 4);
  float* sc1     = (float*)alloc((size_t)32000 * 4);
  float* sc2     = (float*)alloc((size_t)32000 * 4);

  // state buffers alias h2t region (dead after k_bigemm): h0 x2, h1 x3
  u16* h0s[2] = { h2t,                    h2t + (size_t)6144000 };
  u16* h1s[3] = { h2t + (size_t)12288000, h2t + (size_t)18432000, h2t + (size_t)24576000 };
  // FC-head aliases (h0/h1[0..1] dead after k_pool; h1s[2] read by k_pool before fc1 writes hfc)
  u16*   ctxs = h2t;
  float* hfc  = (float*)(h2t + (size_t)18432000);

  k_prep<<<3174, 256, 0, stream>>>(x, fus_W, Wih0, Whh0, Wih1, Whh1, gcn_W1, gcn_b1,
                                   gcn_W2, ln1g, ln1b,
                                   xbf, fusWbf, Wih0b, Whh0b, Wih1b, Whh1b, W2s, cwpk, consts);
  k_w1split<<<144, 256, 0, stream>>>(fc1W, w1s);
  k_zero<<<807, 256, 0, stream>>>(h2t, sc0, sc1, sc2);
  k_adjrow<<<1000, 256, 0, stream>>>(A, FSP, DSP, E1, E2, beta1, beta2, Gbuf, rowsums);
  gemm_nt<0><<<dim3(1, 24), 256, 0, stream>>>(Gbuf, 1000, fusWbf, 1000, Pbuf, 32, 3000, 32, 1000, nullptr);
  k_sc<<<3, 256, 0, stream>>>(Pbuf, fus_b, fus_v, scp);
  k_alpha<<<1, 256, 0, stream>>>(scp, rowsums, alphap, dinvp);
  k_shat<<<4000, 256, 0, stream>>>(Gbuf, alphap, dinvp, Sbf);
  gemm_nt<0><<<dim3(6, 8), 256, 0, stream>>>(Sbf, 1024, xbf, 1000, yt, 384, 1000, 384, 1000, nullptr);
  k_h2gemm<<<3000, 256, 0, stream>>>(yt, cwpk, W2s, consts, h2t);
  // Gg = LN2( S @ h2t^T + b2 )  (73.7 GFLOP, BK=64, fused LN2)
  k_bigemm<<<3072, 256, 0, stream>>>(Sbf, h2t, gcn_b2, ln2g, ln2b, Gg);

  // ---- merged GRU: 13 launches; layer0(u)+fold(u-2) || layer1(u-1) ----
  GruArgs ga;
  ga.Gg = Gg; ga.Wih0 = Wih0b; ga.Whh0 = Whh0b; ga.Wih1 = Wih1b; ga.Whh1 = Whh1b;
  ga.bih0 = bih0; ga.bhh0 = bhh0; ga.bih1 = bih1; ga.bhh1 = bhh1; ga.att_w = att_w;
  ga.h0[0] = h0s[0]; ga.h0[1] = h0s[1];
  ga.h1[0] = h1s[0]; ga.h1[1] = h1s[1]; ga.h1[2] = h1s[2];
  ga.M[0] = Mb0; ga.M[1] = Mb1; ga.L[0] = Lb0; ga.L[1] = Lb1;
  ga.s[0] = sc0; ga.s[1] = sc1; ga.s[2] = sc2;
  ga.Nv = Nv;
  for (int u = 0; u <= 12; ++u)
    k_gru2<<<dim3(12, 250), 256, 0, stream>>>(ga, u);

  // final pool tp=11: h1 state = h1s[11%3=2], score sc2, M/L = post-tp10 (Mb0/Lb0)
  k_pool<<<4000, 256, 0, stream>>>(h1s[2], sc2, Mb0, Lb0, Lb1, Nv);

  // FC head
  k_ctxsplit<<<24000, 256, 0, stream>>>(Nv, Lb1, ctxs);
  gemm_nt<3><<<dim3(3, 250), 256, 0, stream>>>(ctxs, 576, w1s, 576, hfc, 192, 32000, 192, 576, fc1b);
  k_fc2<<<2000, 192, 0, stream>>>(hfc, fc2W, fc2b, out);
}

// Round 14
// 1425.135 us; speedup vs baseline: 3.2632x; 1.0160x over previous
//
#include <hip/hip_runtime.h>

typedef unsigned short u16;
typedef unsigned int u32;
typedef __attribute__((ext_vector_type(8))) short short8;   // 8 x bf16 (4 VGPRs)
typedef __attribute__((ext_vector_type(4))) float float4v;  // 4 x f32

#define DEV static __device__ __forceinline__

DEV float bf2f(u16 u) { u32 x = ((u32)u) << 16; float f; __builtin_memcpy(&f, &x, 4); return f; }
DEV u16 f2bf(float f) {
  u32 u; __builtin_memcpy(&u, &f, 4);
  u = (u + 0x7fffu + ((u >> 16) & 1u)) >> 16;
  return (u16)u;
}
DEV float sigm(float x) { return 1.f / (1.f + __expf(-x)); }

// async global->LDS, 16B per lane; LDS dest = wave-uniform base + lane*16
DEV void gl16(const u16* g, u16* l) {
  __builtin_amdgcn_global_load_lds(
      (const __attribute__((address_space(1))) void*)g,
      (__attribute__((address_space(3))) void*)l, 16, 0, 0);
}

// ============================================================
// Generic GEMM (small cases): C[M,N] = A[M,K](bf16) * B[N,K](bf16 "NK")
// OMODE: 0 = f32 row-major, 3 = f32 + bias + tanh-GELU epilogue (fc1)
// ============================================================
template <int OMODE>
__launch_bounds__(256)
__global__ void gemm_nt(const u16* __restrict__ A, int lda,
                        const u16* __restrict__ B, int ldb,
                        void* __restrict__ Cp, int ldc,
                        int M, int N, int K,
                        const float* __restrict__ bias)
{
  constexpr int PK = 40;
  __shared__ u16 As[128 * PK];
  __shared__ u16 Bs[64 * PK];

  const int tid  = threadIdx.x;
  const int m0   = blockIdx.y * 128;
  const int n0   = blockIdx.x * 64;
  const int wid  = tid >> 6;
  const int lane = tid & 63;
  const int l15  = lane & 15;
  const int quad = lane >> 4;
  const int wm   = (wid >> 1) * 64;
  const int wn   = (wid & 1) * 32;

  float4v acc[4][2];
  const float4v fz = {0.f, 0.f, 0.f, 0.f};
#pragma unroll
  for (int i = 0; i < 4; i++)
#pragma unroll
    for (int j = 0; j < 2; j++) acc[i][j] = fz;

  const int arow = tid >> 2;
  const int akc  = tid & 3;

  const int kt_count = (K + 31) / 32;
  for (int kt = 0; kt < kt_count; ++kt) {
    const int k0 = kt * 32 + akc * 8;
    const bool kok = (k0 < K);
    uint4 av0 = make_uint4(0, 0, 0, 0), av1 = av0, bv = av0;
    int ra = m0 + arow;
    if (kok && ra < M)        av0 = *(const uint4*)(A + (size_t)ra * lda + k0);
    if (kok && ra + 64 < M)   av1 = *(const uint4*)(A + (size_t)(ra + 64) * lda + k0);
    int rb = n0 + arow;
    if (kok && rb < N)        bv  = *(const uint4*)(B + (size_t)rb * ldb + k0);

    __syncthreads();
    *(uint4*)&As[arow * PK + akc * 8]        = av0;
    *(uint4*)&As[(arow + 64) * PK + akc * 8] = av1;
    *(uint4*)&Bs[arow * PK + akc * 8]        = bv;
    __syncthreads();

    short8 af[4], bfr[2];
#pragma unroll
    for (int i = 0; i < 4; i++)
      af[i] = *(const short8*)&As[(wm + i * 16 + l15) * PK + quad * 8];
#pragma unroll
    for (int j = 0; j < 2; j++)
      bfr[j] = *(const short8*)&Bs[(wn + j * 16 + l15) * PK + quad * 8];
#pragma unroll
    for (int i = 0; i < 4; i++)
#pragma unroll
      for (int j = 0; j < 2; j++)
        acc[i][j] = __builtin_amdgcn_mfma_f32_16x16x32_bf16(af[i], bfr[j], acc[i][j], 0, 0, 0);
  }

#pragma unroll
  for (int i = 0; i < 4; i++)
#pragma unroll
    for (int j = 0; j < 2; j++)
#pragma unroll
      for (int e = 0; e < 4; e++) {
        int r = m0 + wm + i * 16 + quad * 4 + e;
        int c = n0 + wn + j * 16 + l15;
        if (r < M && c < N) {
          float v = acc[i][j][e];
          if (OMODE == 0) ((float*)Cp)[(size_t)r * ldc + c] = v;
          else {
            float a = v + bias[c];
            float t = tanhf(0.7978845608028654f * (a + 0.044715f * a * a * a));
            ((float*)Cp)[(size_t)r * ldc + c] = 0.5f * a * (1.f + t);
          }
        }
      }
}

// ============================================================
// Big graph-conv GEMM + fused LN2: BK=64 (16 barrier iters), gl16,
// XOR swizzle, XCD swizzle; writes LN2'd bf16 in GRU g-layout.
// ============================================================
__launch_bounds__(256)
__global__ void k_bigemm(const u16* __restrict__ A,    // Sbf 1024x1024
                         const u16* __restrict__ B,    // h2t 36864x1024
                         const float* __restrict__ b2, const float* __restrict__ g2,
                         const float* __restrict__ be2,
                         u16* __restrict__ Gg)
{
  __shared__ u16 As[128 * 64];
  __shared__ u16 Bs[96 * 64];
  __shared__ float stats[2][2][128];

  const int tid  = threadIdx.x;
  const int bid  = blockIdx.x;
  const int xcd  = bid & 7;
  const int jj   = bid >> 3;
  const int m0   = (jj & 7) * 128;
  const int rt   = xcd + 8 * (jj >> 3);

  const int wid  = tid >> 6;
  const int lane = tid & 63;
  const int l15  = lane & 15;
  const int quad = lane >> 4;
  const int wm   = (wid >> 1) * 64;
  const int wn   = (wid & 1) * 48;
  const int wni  = wid & 1;

  const int srow8 = lane >> 3;
  const int sw8   = ((lane & 7) ^ srow8) * 8;

  const u16* abase = A + (size_t)(m0 + wid * 8 + srow8) * 1024 + sw8;
  const u16* bbase = B + (size_t)(rt * 96 + wid * 8 + srow8) * 1024 + sw8;

  float4v acc[4][3];
  const float4v fz = {0.f, 0.f, 0.f, 0.f};
#pragma unroll
  for (int i = 0; i < 4; i++)
#pragma unroll
    for (int j = 0; j < 3; j++) acc[i][j] = fz;

  for (int kt = 0; kt < 16; ++kt) {
    const int ko = kt * 64;
#pragma unroll
    for (int c = 0; c < 4; c++)
      gl16(abase + (size_t)c * 32 * 1024 + ko, &As[(c * 32 + wid * 8) * 64]);
#pragma unroll
    for (int c = 0; c < 3; c++)
      gl16(bbase + (size_t)c * 32 * 1024 + ko, &Bs[(c * 32 + wid * 8) * 64]);
    __syncthreads();
#pragma unroll
    for (int k32 = 0; k32 < 2; k32++) {
      const int swr = ((quad + 4 * k32) ^ (l15 & 7)) * 8;
      short8 af[4], bf[3];
#pragma unroll
      for (int i = 0; i < 4; i++)
        af[i] = *(const short8*)&As[(wm + i * 16 + l15) * 64 + swr];
#pragma unroll
      for (int j = 0; j < 3; j++)
        bf[j] = *(const short8*)&Bs[(wn + j * 16 + l15) * 64 + swr];
#pragma unroll
      for (int i = 0; i < 4; i++)
#pragma unroll
        for (int j = 0; j < 3; j++)
          acc[i][j] = __builtin_amdgcn_mfma_f32_16x16x32_bf16(af[i], bf[j], acc[i][j], 0, 0, 0);
    }
    __syncthreads();
  }

  // ---- fused LN2 epilogue ----
  float b2v[3], g2v[3], bev[3];
#pragma unroll
  for (int j = 0; j < 3; j++) {
    int c = wn + j * 16 + l15;
    b2v[j] = b2[c]; g2v[j] = g2[c]; bev[j] = be2[c];
  }
#pragma unroll
  for (int i = 0; i < 4; i++)
#pragma unroll
    for (int e = 0; e < 4; e++) {
      float s = 0.f, ss = 0.f;
#pragma unroll
      for (int j = 0; j < 3; j++) {
        float v = acc[i][j][e] + b2v[j];
        acc[i][j][e] = v;
        s += v; ss += v * v;
      }
      s += __shfl_xor(s, 1); ss += __shfl_xor(ss, 1);
      s += __shfl_xor(s, 2); ss += __shfl_xor(ss, 2);
      s += __shfl_xor(s, 4); ss += __shfl_xor(ss, 4);
      s += __shfl_xor(s, 8); ss += __shfl_xor(ss, 8);
      if (l15 == 0) {
        int rl = wm + i * 16 + quad * 4 + e;
        stats[wni][0][rl] = s;
        stats[wni][1][rl] = ss;
      }
    }
  __syncthreads();
#pragma unroll
  for (int i = 0; i < 4; i++)
#pragma unroll
    for (int e = 0; e < 4; e++) {
      int rl = wm + i * 16 + quad * 4 + e;
      int m = m0 + rl;
      if (m < 1000) {
        float ts  = stats[0][0][rl] + stats[1][0][rl];
        float tss = stats[0][1][rl] + stats[1][1][rl];
        float mean = ts * (1.f / 96.f);
        float var  = tss * (1.f / 96.f) - mean * mean;
        float isd  = rsqrtf(var + 1e-5f);
#pragma unroll
        for (int j = 0; j < 3; j++) {
          int c = wn + j * 16 + l15;
          Gg[(size_t)rt * 96000 + (size_t)m * 96 + c] =
              f2bf((acc[i][j][e] - mean) * isd * g2v[j] + bev[j]);
        }
      }
    }
}

// ============================================================
// Online-softmax pool fold for timestep tp (tile m0/c0 owns 128q x 32c).
// pm: 1 = init (tp==0), 2 = normal.
// ============================================================
DEV void pool_fold(int m0, int c0, int pm,
                   const u16* __restrict__ Hpool,
                   const float* __restrict__ score_rd,
                   const float* __restrict__ Mrd, const float* __restrict__ Lrd,
                   float* __restrict__ Mwr, float* __restrict__ Lwr,
                   float* __restrict__ Nvp)
{
  const int tid = threadIdx.x;
#pragma unroll
  for (int k = 0; k < 16; k++) {
    int idx = k * 256 + tid;
    int ql = idx >> 5, cl = idx & 31;
    int q = m0 + ql, c = c0 + cl;
    size_t nidx = (size_t)q * 192 + c;
    float s = score_rd[q];
    float hnew = bf2f(Hpool[nidx]);
    float so, wnf, prev;
    if (pm == 1) { so = 0.f; wnf = 1.f; prev = 0.f; }
    else {
      float Mo = Mrd[q];
      float Mn = fmaxf(Mo, s);
      so = __expf(Mo - Mn); wnf = __expf(s - Mn);
      prev = Nvp[nidx];
    }
    Nvp[nidx] = prev * so + wnf * hnew;
  }
  if (c0 == 0 && tid < 128) {
    int q = m0 + tid;
    float s = score_rd[q];
    if (pm == 1) { Mwr[q] = s; Lwr[q] = 1.f; }
    else {
      float Mo = Mrd[q], Mn = fmaxf(Mo, s);
      Mwr[q] = Mn;
      Lwr[q] = Lrd[q] * __expf(Mo - Mn) + __expf(s - Mn);
    }
  }
}

// ============================================================
// GRU tile device function. BM=128, 32 cols/gate.
// K=192 phases BK=64; K=96 X-phase BK=32. XOR-swizzled LDS.
// ============================================================
template <int KX, bool POOL>
DEV void gru_tile(u16* As, u16* Bs,
                  int m0, int c0,
                  const u16* __restrict__ Xin, int ldx,
                  const u16* __restrict__ Win,
                  const u16* __restrict__ Hin,
                  const u16* __restrict__ Whh,
                  const float* __restrict__ bih, const float* __restrict__ bhh,
                  u16* __restrict__ Hout,
                  const float* __restrict__ att_w,
                  float* __restrict__ score_acc,
                  const u16* __restrict__ Hpool,
                  const float* __restrict__ score_rd,
                  const float* __restrict__ Mrd, const float* __restrict__ Lrd,
                  float* __restrict__ Mwr, float* __restrict__ Lwr,
                  float* __restrict__ Nvp,
                  int t0, int pm)
{
  const int tid  = threadIdx.x;
  const int wid  = tid >> 6;
  const int lane = tid & 63;
  const int l15  = lane & 15;
  const int quad = lane >> 4;
  const int wm   = wid * 32;

  // ---- folded pool (layer0 part, timestep u-2) ----
  if (!POOL && pm)
    pool_fold(m0, c0, pm, Hpool, score_rd, Mrd, Lrd, Mwr, Lwr, Nvp);

  const int srow8 = lane >> 3;
  const int sw8   = ((lane & 7) ^ srow8) * 8;
  const int srow4 = lane >> 2;
  const int sw4   = ((lane & 3) ^ ((lane >> 3) & 3)) * 8;

  float4v aR[2][2], aZ[2][2], aXN[2][2], aHN[2][2];
  const float4v fz = {0.f, 0.f, 0.f, 0.f};
#pragma unroll
  for (int i = 0; i < 2; i++)
#pragma unroll
    for (int j = 0; j < 2; j++) { aR[i][j] = fz; aZ[i][j] = fz; aXN[i][j] = fz; aHN[i][j] = fz; }

  // ---- phase X ----
  if (KX == 96) {
    const u16* ax0 = Xin + (size_t)(m0 + wid * 16 + srow4) * ldx + sw4;
    const u16* ax1 = Xin + (size_t)(m0 + 64 + wid * 16 + srow4) * ldx + sw4;
    const int b0 = wid * 16 + srow4;
    const u16* bx0 = Win + (size_t)((b0 >> 5) * 192 + c0 + (b0 & 31)) * 96 + sw4;
    const int b1 = 64 + wid * 16 + srow4;
    const u16* bx1 = Win + (size_t)(384 + c0 + (b1 & 31)) * 96 + sw4;
    u16* asl0 = &As[(wid * 16) * 32];
    u16* asl1 = &As[(64 + wid * 16) * 32];
    u16* bsl0 = &Bs[(wid * 16) * 32];
    u16* bsl1 = &Bs[(64 + wid * 16) * 32];
    const int swa = (quad ^ ((l15 >> 1) & 3)) * 8;
#pragma unroll
    for (int kt = 0; kt < 3; ++kt) {
      const int ko = kt * 32;
      gl16(ax0 + ko, asl0); gl16(ax1 + ko, asl1);
      gl16(bx0 + ko, bsl0);
      if (wid < 2) gl16(bx1 + ko, bsl1);
      __syncthreads();
      short8 af[2], bR[2], bZ[2], bN[2];
#pragma unroll
      for (int i = 0; i < 2; i++)
        af[i] = *(const short8*)&As[(wm + i * 16 + l15) * 32 + swa];
#pragma unroll
      for (int j = 0; j < 2; j++) {
        bR[j] = *(const short8*)&Bs[(j * 16 + l15) * 32 + swa];
        bZ[j] = *(const short8*)&Bs[(32 + j * 16 + l15) * 32 + swa];
        bN[j] = *(const short8*)&Bs[(64 + j * 16 + l15) * 32 + swa];
      }
#pragma unroll
      for (int i = 0; i < 2; i++)
#pragma unroll
        for (int j = 0; j < 2; j++) {
          aR[i][j]  = __builtin_amdgcn_mfma_f32_16x16x32_bf16(af[i], bR[j], aR[i][j], 0, 0, 0);
          aZ[i][j]  = __builtin_amdgcn_mfma_f32_16x16x32_bf16(af[i], bZ[j], aZ[i][j], 0, 0, 0);
          aXN[i][j] = __builtin_amdgcn_mfma_f32_16x16x32_bf16(af[i], bN[j], aXN[i][j], 0, 0, 0);
        }
      __syncthreads();
    }
  } else {
    const u16* abase = Xin + (size_t)(m0 + wid * 8 + srow8) * 192 + sw8;
    const u16* bbase = Win + (size_t)(c0 + wid * 8 + srow8) * 192 + sw8;
#pragma unroll
    for (int kt = 0; kt < 3; ++kt) {
      const int ko = kt * 64;
#pragma unroll
      for (int c = 0; c < 4; c++)
        gl16(abase + (size_t)c * 32 * 192 + ko, &As[(c * 32 + wid * 8) * 64]);
#pragma unroll
      for (int c = 0; c < 3; c++)
        gl16(bbase + (size_t)c * 192 * 192 + ko, &Bs[(c * 32 + wid * 8) * 64]);
      __syncthreads();
#pragma unroll
      for (int k32 = 0; k32 < 2; k32++) {
        const int swr = ((quad + 4 * k32) ^ (l15 & 7)) * 8;
        short8 af[2], bR[2], bZ[2], bN[2];
#pragma unroll
        for (int i = 0; i < 2; i++)
          af[i] = *(const short8*)&As[(wm + i * 16 + l15) * 64 + swr];
#pragma unroll
        for (int j = 0; j < 2; j++) {
          bR[j] = *(const short8*)&Bs[(j * 16 + l15) * 64 + swr];
          bZ[j] = *(const short8*)&Bs[(32 + j * 16 + l15) * 64 + swr];
          bN[j] = *(const short8*)&Bs[(64 + j * 16 + l15) * 64 + swr];
        }
#pragma unroll
        for (int i = 0; i < 2; i++)
#pragma unroll
          for (int j = 0; j < 2; j++) {
            aR[i][j]  = __builtin_amdgcn_mfma_f32_16x16x32_bf16(af[i], bR[j], aR[i][j], 0, 0, 0);
            aZ[i][j]  = __builtin_amdgcn_mfma_f32_16x16x32_bf16(af[i], bZ[j], aZ[i][j], 0, 0, 0);
            aXN[i][j] = __builtin_amdgcn_mfma_f32_16x16x32_bf16(af[i], bN[j], aXN[i][j], 0, 0, 0);
          }
      }
      __syncthreads();
    }
  }
  // ---- phase H: K=192, BK=64 x 3 ----
  if (!t0) {
    const u16* abase = Hin + (size_t)(m0 + wid * 8 + srow8) * 192 + sw8;
    const u16* bbase = Whh + (size_t)(c0 + wid * 8 + srow8) * 192 + sw8;
#pragma unroll
    for (int kt = 0; kt < 3; ++kt) {
      const int ko = kt * 64;
#pragma unroll
      for (int c = 0; c < 4; c++)
        gl16(abase + (size_t)c * 32 * 192 + ko, &As[(c * 32 + wid * 8) * 64]);
#pragma unroll
      for (int c = 0; c < 3; c++)
        gl16(bbase + (size_t)c * 192 * 192 + ko, &Bs[(c * 32 + wid * 8) * 64]);
      __syncthreads();
#pragma unroll
      for (int k32 = 0; k32 < 2; k32++) {
        const int swr = ((quad + 4 * k32) ^ (l15 & 7)) * 8;
        short8 af[2], bR[2], bZ[2], bN[2];
#pragma unroll
        for (int i = 0; i < 2; i++)
          af[i] = *(const short8*)&As[(wm + i * 16 + l15) * 64 + swr];
#pragma unroll
        for (int j = 0; j < 2; j++) {
          bR[j] = *(const short8*)&Bs[(j * 16 + l15) * 64 + swr];
          bZ[j] = *(const short8*)&Bs[(32 + j * 16 + l15) * 64 + swr];
          bN[j] = *(const short8*)&Bs[(64 + j * 16 + l15) * 64 + swr];
        }
#pragma unroll
        for (int i = 0; i < 2; i++)
#pragma unroll
          for (int j = 0; j < 2; j++) {
            aR[i][j]  = __builtin_amdgcn_mfma_f32_16x16x32_bf16(af[i], bR[j], aR[i][j], 0, 0, 0);
            aZ[i][j]  = __builtin_amdgcn_mfma_f32_16x16x32_bf16(af[i], bZ[j], aZ[i][j], 0, 0, 0);
            aHN[i][j] = __builtin_amdgcn_mfma_f32_16x16x32_bf16(af[i], bN[j], aHN[i][j], 0, 0, 0);
          }
      }
      __syncthreads();
    }
  }

  // ---- epilogue: gates + state write (+ pooling partials) ----
  float ps[2][4];
  if (POOL) {
#pragma unroll
    for (int i = 0; i < 2; i++)
#pragma unroll
      for (int e = 0; e < 4; e++) ps[i][e] = 0.f;
  }
#pragma unroll
  for (int j = 0; j < 2; ++j) {
    const int c = c0 + j * 16 + l15;
    const float brz = bih[c] + bhh[c];
    const float bzz = bih[192 + c] + bhh[192 + c];
    const float bxn = bih[384 + c];
    const float bhn = bhh[384 + c];
    const float aw  = POOL ? att_w[c] : 0.f;
#pragma unroll
    for (int i = 0; i < 2; ++i)
#pragma unroll
      for (int e = 0; e < 4; ++e) {
        const int row = m0 + wm + i * 16 + quad * 4 + e;
        float rg  = sigm(aR[i][j][e] + brz);
        float zg  = sigm(aZ[i][j][e] + bzz);
        float hnv = bhn + (t0 ? 0.f : aHN[i][j][e]);
        float ng  = tanhf(aXN[i][j][e] + bxn + rg * hnv);
        float hold = t0 ? 0.f : bf2f(Hin[(size_t)row * 192 + c]);
        float hnew = (1.f - zg) * ng + zg * hold;
        Hout[(size_t)row * 192 + c] = f2bf(hnew);
        if (POOL) ps[i][e] += hnew * aw;
      }
  }
  if (POOL) {
#pragma unroll
    for (int i = 0; i < 2; ++i)
#pragma unroll
      for (int e = 0; e < 4; ++e) {
        float v = ps[i][e];
        v += __shfl_xor(v, 1); v += __shfl_xor(v, 2);
        v += __shfl_xor(v, 4); v += __shfl_xor(v, 8);
        if (l15 == 0) atomicAdd(&score_acc[m0 + wm + i * 16 + quad * 4 + e], v);
      }
  }
}

// ============================================================
// Merged GRU launch u (0..12): x<6 -> layer0(step u) + fold(u-2),
// x>=6 -> layer1(step u-1). At u=12 the layer0 branch is fold-only (tp=10).
// ============================================================
struct GruArgs {
  const u16 *Gg, *Wih0, *Whh0, *Wih1, *Whh1;
  const float *bih0, *bhh0, *bih1, *bhh1, *att_w;
  u16 *h0[2];
  u16 *h1[3];
  float *M[2], *L[2], *s[3];
  float* Nv;
};

__launch_bounds__(256)
__global__ void k_gru2(GruArgs a, int u)
{
  __shared__ u16 As[128 * 64];
  __shared__ u16 Bs[96 * 64];
  const int m0 = blockIdx.y * 128;

  if (blockIdx.x < 6) {
    const int c0 = blockIdx.x * 32;
    const int pm = (u < 2) ? 0 : (u == 2 ? 1 : 2);
    if (u > 11) {
      if (pm)
        pool_fold(m0, c0, pm, a.h1[(u + 1) % 3], a.s[(u + 1) % 3],
                  a.M[(u + 1) & 1], a.L[(u + 1) & 1], a.M[u & 1], a.L[u & 1], a.Nv);
      return;
    }
    if (c0 == 0 && threadIdx.x < 128) a.s[u % 3][m0 + threadIdx.x] = 0.f;
    gru_tile<96, false>(As, Bs, m0, c0,
        a.Gg + u * 96, 1152, a.Wih0, a.h0[u & 1], a.Whh0, a.bih0, a.bhh0, a.h0[(u & 1) ^ 1],
        nullptr, nullptr,
        a.h1[(u + 1) % 3], a.s[(u + 1) % 3],
        a.M[(u + 1) & 1], a.L[(u + 1) & 1],
        a.M[u & 1], a.L[u & 1],
        a.Nv, u == 0, pm);
  } else {
    if (u < 1) return;
    const int t = u - 1;
    const int c0 = (blockIdx.x - 6) * 32;
    gru_tile<192, true>(As, Bs, m0, c0,
        a.h0[u & 1], 192, a.Wih1, a.h1[(u + 1) % 3], a.Whh1, a.bih1, a.bhh1, a.h1[t % 3],
        a.att_w, a.s[t % 3],
        nullptr, nullptr, nullptr, nullptr, nullptr, nullptr, nullptr,
        t == 0, 0);
  }
}

// ============================================================
// H2 GEMM: h2t[(r*96+c2)*1024+n] = Hln @ W2 (analytic LN1 in A-staging)
// ============================================================
__launch_bounds__(256)
__global__ void k_h2gemm(const float* __restrict__ yt, const float4* __restrict__ cwpk,
                         const u16* __restrict__ W2s, const float* __restrict__ consts,
                         u16* __restrict__ h2t)
{
  constexpr int PK = 40;
  __shared__ u16 As[128 * PK];
  __shared__ u16 Bs[96 * PK];
  __shared__ u16 Ts[96 * 136];

  const int tid  = threadIdx.x;
  const int m0   = blockIdx.x * 128;
  const int wid  = tid >> 6;
  const int lane = tid & 63;
  const int l15  = lane & 15;
  const int quad = lane >> 4;
  const int wm   = (wid >> 1) * 64;
  const int wn   = (wid & 1) * 48;

  const float P = consts[0], Q = consts[1], VW = consts[2], CWB = consts[3], VB = consts[4];

  const int arow = tid >> 2;
  const int akc  = tid & 3;

  float yv[2], mu[2], iv[2];
#pragma unroll
  for (int rr = 0; rr < 2; rr++) {
    int i = m0 + arow + rr * 64;
    int r = i / 1000, n = i - r * 1000;
    float y = yt[n * 384 + r];
    yv[rr] = y;
    mu[rr] = y * P + Q;
    iv[rr] = rsqrtf(y * y * VW + 2.f * y * CWB + VB + 1e-5f);
  }

  float4v acc[4][3];
  const float4v fz = {0.f, 0.f, 0.f, 0.f};
#pragma unroll
  for (int i = 0; i < 4; i++)
#pragma unroll
    for (int j = 0; j < 3; j++) acc[i][j] = fz;

  uint4 asave[2][3];
  const bool has2 = (arow < 32);

  for (int kt = 0; kt < 6; ++kt) {
    const int k0 = kt * 32 + akc * 8;
    uint4 av[2];
    if (kt < 3) {
#pragma unroll
      for (int rr = 0; rr < 2; rr++) {
        u16 hb[8];
#pragma unroll
        for (int e = 0; e < 8; e++) {
          float4 cw = cwpk[k0 + e];
          float t = yv[rr] * cw.x + cw.y - mu[rr];
          float h = fmaxf(t * iv[rr] * cw.z + cw.w, 0.f);
          hb[e] = f2bf(h);
        }
        __builtin_memcpy(&av[rr], hb, 16);
        asave[rr][kt] = av[rr];
      }
    } else {
      av[0] = asave[0][kt - 3];
      av[1] = asave[1][kt - 3];
    }
    uint4 bv0 = *(const uint4*)(W2s + (size_t)arow * 192 + k0);
    uint4 bv1 = make_uint4(0, 0, 0, 0);
    if (has2) bv1 = *(const uint4*)(W2s + (size_t)(arow + 64) * 192 + k0);

    __syncthreads();
    *(uint4*)&As[arow * PK + akc * 8]        = av[0];
    *(uint4*)&As[(arow + 64) * PK + akc * 8] = av[1];
    *(uint4*)&Bs[arow * PK + akc * 8]        = bv0;
    if (has2) *(uint4*)&Bs[(arow + 64) * PK + akc * 8] = bv1;
    __syncthreads();

    short8 af[4], bfr[3];
#pragma unroll
    for (int i = 0; i < 4; i++)
      af[i] = *(const short8*)&As[(wm + i * 16 + l15) * PK + quad * 8];
#pragma unroll
    for (int j = 0; j < 3; j++)
      bfr[j] = *(const short8*)&Bs[(wn + j * 16 + l15) * PK + quad * 8];
#pragma unroll
    for (int i = 0; i < 4; i++)
#pragma unroll
      for (int j = 0; j < 3; j++)
        acc[i][j] = __builtin_amdgcn_mfma_f32_16x16x32_bf16(af[i], bfr[j], acc[i][j], 0, 0, 0);
  }

#pragma unroll
  for (int i = 0; i < 4; i++)
#pragma unroll
    for (int j = 0; j < 3; j++)
#pragma unroll
      for (int e = 0; e < 4; e++) {
        int rowl = wm + i * 16 + quad * 4 + e;
        int c2   = wn + j * 16 + l15;
        Ts[c2 * 136 + rowl] = f2bf(acc[i][j][e]);
      }
  __syncthreads();
#pragma unroll
  for (int u = tid; u < 1536; u += 256) {
    int c2 = u >> 4, ch = u & 15;
    int iidx0 = m0 + ch * 8;
    int r = iidx0 / 1000, n0 = iidx0 - r * 1000;
    *(uint4*)(h2t + (size_t)(r * 96 + c2) * 1024 + n0) = *(const uint4*)&Ts[c2 * 136 + ch * 8];
  }
}

// ============================================================
// prep: all f32->bf16 conversions, W1/b1 moments, W2 split, cw pack,
// fc1W split, fusW transpose (f32), h2t K-pad zero, score/sc zero.
// ============================================================
__launch_bounds__(256)
__global__ void k_prep(const float* x, const float* fus_W,
                       const float* Wih0, const float* Whh0,
                       const float* Wih1, const float* Whh1,
                       const float* gcn_W1, const float* gcn_b1,
                       const float* gcn_W2, const float* ln1g, const float* ln1b,
                       const float* fc1W,
                       u16* xbf, u16* fusWbf, u16* Wih0b, u16* Whh0b, u16* Wih1b, u16* Whh1b,
                       u16* W2s, float4* cwpk, float* scp, u16* w1s, float* fusWT,
                       u16* h2t, float* s0, float* s1, float* s2, float* consts)
{
  long o = (long)blockIdx.x * 256 + threadIdx.x;
  if (o < 384000) xbf[o] = f2bf(x[o]);
  else if ((o -= 384000) < 32000) fusWbf[o] = f2bf(fus_W[o]);
  else if ((o -= 32000) < 55296)  Wih0b[o] = f2bf(Wih0[o]);
  else if ((o -= 55296) < 110592) Whh0b[o] = f2bf(Whh0[o]);
  else if ((o -= 110592) < 110592) Wih1b[o] = f2bf(Wih1[o]);
  else if ((o -= 110592) < 110592) Whh1b[o] = f2bf(Whh1[o]);
  else if ((o -= 110592) < 9216) {
    int c2 = (int)o / 96, c = (int)o - c2 * 96;
    float wv = gcn_W2[c * 96 + c2];
    u16 hi = f2bf(wv);
    u16 lo = f2bf(wv - bf2f(hi));
    W2s[c2 * 192 + c] = hi;
    W2s[c2 * 192 + 96 + c] = lo;
  }
  else if ((o -= 9216) < 96) {
    int c = (int)o;
    float4 cw;
    cw.x = gcn_W1[c]; cw.y = gcn_b1[c]; cw.z = ln1g[c]; cw.w = ln1b[c];
    cwpk[c] = cw;
  }
  else if ((o -= 96) < 3) scp[o] = 0.f;
  else if ((o -= 3) < 36864) {
    int n = (int)o / 192, k = (int)o - n * 192;
    float wv = fc1W[o];
    u16 hi = f2bf(wv);
    u16 lo = f2bf(wv - bf2f(hi));
    w1s[(size_t)n * 576 + k]       = hi;
    w1s[(size_t)n * 576 + 192 + k] = lo;
    w1s[(size_t)n * 576 + 384 + k] = hi;
  }
  else if ((o -= 36864) < 32000) {
    int m = (int)o >> 5, a = (int)o & 31;
    fusWT[o] = fus_W[a * 1000 + m];
  }
  else if ((o -= 32000) < 110592) {
    int row = (int)o / 3, p = (int)o - row * 3;
    *(uint4*)(h2t + (size_t)row * 1024 + 1000 + p * 8) = make_uint4(0, 0, 0, 0);
  }
  else if ((o -= 110592) < 96000) {
    if (o < 32000) s0[o] = 0.f;
    else if (o < 64000) s1[o - 32000] = 0.f;
    else s2[o - 64000] = 0.f;
  }
  if (blockIdx.x == 0 && threadIdx.x == 0) {
    float sw = 0, sb = 0, sww = 0, swb = 0, sbb = 0;
    for (int c = 0; c < 96; c++) {
      float wv = gcn_W1[c], b = gcn_b1[c];
      sw += wv; sb += b; sww += wv * wv; swb += wv * b; sbb += b * b;
    }
    float P = sw / 96.f, Q = sb / 96.f;
    consts[0] = P; consts[1] = Q;
    consts[2] = sww / 96.f - P * P;
    consts[3] = swb / 96.f - P * Q;
    consts[4] = sbb / 96.f - Q * Q;
  }
}

// ============================================================
// per-row: Aadp softmax + 3 candidate graphs + row sums + fused
// P = G @ fusW^T and sc contribution (atomicAdd into scp).
// ============================================================
__launch_bounds__(256)
__global__ void k_adjrow(const float* __restrict__ A, const float* __restrict__ FSP,
                         const float* __restrict__ DSP, const float* __restrict__ E1,
                         const float* __restrict__ E2,
                         const float* beta1, const float* beta2,
                         const float* __restrict__ fusWT,
                         const float* __restrict__ fus_b, const float* __restrict__ fus_v,
                         u16* __restrict__ G, float* __restrict__ rowsums,
                         float* __restrict__ scp)
{
  __shared__ float z[1000];
  __shared__ float red[256];
  __shared__ float gk[3000];
  __shared__ float pred[768];     // [k*256 + a*8 + grp]
  __shared__ float vred[96];
  const int n = blockIdx.x, tid = threadIdx.x;

  float e1r[10];
#pragma unroll
  for (int d = 0; d < 10; d++) e1r[d] = E1[n * 10 + d];

  float lmax = -1e30f;
  for (int m = tid; m < 1000; m += 256) {
    float s = 0;
#pragma unroll
    for (int d = 0; d < 10; d++) s += e1r[d] * E2[m * 10 + d];
    s = fmaxf(s, 0.f);
    z[m] = s;
    lmax = fmaxf(lmax, s);
  }
  red[tid] = lmax; __syncthreads();
  for (int st = 128; st > 0; st >>= 1) { if (tid < st) red[tid] = fmaxf(red[tid], red[tid + st]); __syncthreads(); }
  const float mx = red[0]; __syncthreads();

  float lsum = 0;
  for (int m = tid; m < 1000; m += 256) { float e = __expf(z[m] - mx); z[m] = e; lsum += e; }
  red[tid] = lsum; __syncthreads();
  for (int st = 128; st > 0; st >>= 1) { if (tid < st) red[tid] += red[tid + st]; __syncthreads(); }
  const float inv = 1.f / red[0]; __syncthreads();

  const float w1 = sigm(beta1[0]);
  const float w2 = sigm(beta2[0]);
  float s0 = 0, s1 = 0, s2 = 0;
  for (int m = tid; m < 1000; m += 256) {
    float aadp = z[m] * inv;
    float a = A[n * 1000 + m], f = FSP[n * 1000 + m], dd = DSP[n * 1000 + m];
    float g0 = 0.5f * a + 0.5f * aadp;
    float g1 = w1 * a + (1.f - w1) * f;
    float g2 = w2 * a + (1.f - w2) * dd;
    G[0 * 1000000 + n * 1000 + m] = f2bf(g0);
    G[1 * 1000000 + n * 1000 + m] = f2bf(g1);
    G[2 * 1000000 + n * 1000 + m] = f2bf(g2);
    gk[m] = g0; gk[1000 + m] = g1; gk[2000 + m] = g2;
    s0 += g0; s1 += g1; s2 += g2;
  }
  red[tid] = s0; __syncthreads();
  for (int st = 128; st > 0; st >>= 1) { if (tid < st) red[tid] += red[tid + st]; __syncthreads(); }
  if (tid == 0) rowsums[n] = red[0];
  __syncthreads();
  red[tid] = s1; __syncthreads();
  for (int st = 128; st > 0; st >>= 1) { if (tid < st) red[tid] += red[tid + st]; __syncthreads(); }
  if (tid == 0) rowsums[1000 + n] = red[0];
  __syncthreads();
  red[tid] = s2; __syncthreads();
  for (int st = 128; st > 0; st >>= 1) { if (tid < st) red[tid] += red[tid + st]; __syncthreads(); }
  if (tid == 0) rowsums[2000 + n] = red[0];
  __syncthreads();

  // ---- fused P + sc: thread = (a, grp); P[k,a] = sum_m gk[m]*fusWT[m*32+a]
  const int a = tid & 31, grp = tid >> 5;
  float p0 = 0.f, p1 = 0.f, p2 = 0.f;
  for (int m = grp; m < 1000; m += 8) {
    float wv = fusWT[m * 32 + a];
    p0 += gk[m] * wv;
    p1 += gk[1000 + m] * wv;
    p2 += gk[2000 + m] * wv;
  }
  pred[0 * 256 + a * 8 + grp] = p0;
  pred[1 * 256 + a * 8 + grp] = p1;
  pred[2 * 256 + a * 8 + grp] = p2;
  __syncthreads();
  if (tid < 96) {
    int k = tid >> 5, aa = tid & 31;
    float P = 0.f;
#pragma unroll
    for (int g = 0; g < 8; g++) P += pred[k * 256 + aa * 8 + g];
    vred[k * 32 + aa] = tanhf(P + fus_b[aa]) * fus_v[aa];
  }
  __syncthreads();
  if (tid < 3) {
    float s = 0.f;
#pragma unroll
    for (int aa = 0; aa < 32; aa++) s += vred[tid * 32 + aa];
    atomicAdd(&scp[tid], s * 0.001f);
  }
}

__launch_bounds__(256)
__global__ void k_alpha(const float* sc, const float* rowsums, float* alpha_out, float* dinv)
{
  __shared__ float al[3];
  const int tid = threadIdx.x;
  if (tid == 0) {
    float m = fmaxf(sc[0], fmaxf(sc[1], sc[2]));
    float e0 = __expf(sc[0] - m), e1 = __expf(sc[1] - m), e2 = __expf(sc[2] - m);
    float inv = 1.f / (e0 + e1 + e2);
    al[0] = e0 * inv; al[1] = e1 * inv; al[2] = e2 * inv;
    alpha_out[0] = al[0]; alpha_out[1] = al[1]; alpha_out[2] = al[2];
  }
  __syncthreads();
  const float a0 = al[0], a1 = al[1], a2 = al[2];
  for (int n = tid; n < 1000; n += 256) {
    float d = a0 * rowsums[n] + a1 * rowsums[1000 + n] + a2 * rowsums[2000 + n] + 1.0f;
    dinv[n] = rsqrtf(fmaxf(d, 1e-12f));
  }
}

// S_hat -> Sbf with 1024 K-pad stride (pad cols zeroed)
__launch_bounds__(256)
__global__ void k_shat(const u16* __restrict__ G, const float* alpha, const float* dinv,
                       u16* __restrict__ S)
{
  int idx = blockIdx.x * 256 + threadIdx.x;
  if (idx >= 1024000) return;
  int i = idx >> 10, j = idx & 1023;
  u16 val = 0;
  if (j < 1000) {
    const float a0 = alpha[0], a1 = alpha[1], a2 = alpha[2];
    int g = i * 1000 + j;
    float mg = a0 * bf2f(G[g]) + a1 * bf2f(G[1000000 + g]) + a2 * bf2f(G[2000000 + g]);
    if (i == j) mg += 1.0f;
    val = f2bf(mg * dinv[i] * dinv[j]);
  }
  S[(size_t)i * 1024 + j] = val;
}

// ctx with fused final pool (tp=11): v = (Nv*so + wn*h)/L, split hi/lo bf16
__launch_bounds__(256)
__global__ void k_ctxsplit(const float* __restrict__ Nv, const u16* __restrict__ Hlast,
                           const float* __restrict__ score_rd,
                           const float* __restrict__ Mrd, const float* __restrict__ Lrd,
                           u16* __restrict__ ctxs)
{
  const int i = blockIdx.x * 256 + threadIdx.x;
  if (i >= 32000 * 192) return;
  const int q = i / 192, c = i - q * 192;
  const float s = score_rd[q];
  const float Mo = Mrd[q];
  const float Mn = fmaxf(Mo, s);
  const float so = __expf(Mo - Mn);
  const float wn = __expf(s - Mn);
  const float L = Lrd[q] * so + wn;
  float v = (Nv[i] * so + wn * bf2f(Hlast[i])) / L;
  u16 hi = f2bf(v);
  u16 lo = f2bf(v - bf2f(hi));
  u16* row = ctxs + (size_t)q * 576;
  row[c] = hi; row[192 + c] = hi; row[384 + c] = lo;
}

// fc2: LDS-staged tiny GEMM + transposed store
__launch_bounds__(192)
__global__ void k_fc2(const float* __restrict__ hfc, const float* __restrict__ fc2W,
                      const float* __restrict__ fc2b, float* __restrict__ out)
{
  __shared__ float w2S[12][193];
  __shared__ float hS[16][193];
  const int tid = threadIdx.x;
  const int q0 = blockIdx.x * 16;
  for (int idx = tid; idx < 12 * 192; idx += 192) {
    int o = idx / 192, k = idx - o * 192;
    w2S[o][k] = fc2W[idx];
  }
  for (int idx = tid; idx < 16 * 192; idx += 192) {
    int qq = idx / 192, k = idx - qq * 192;
    hS[qq][k] = hfc[(size_t)(q0 + qq) * 192 + k];
  }
  __syncthreads();
  const int qq = tid / 12, o = tid - qq * 12;
  float acc = fc2b[o];
#pragma unroll 8
  for (int k = 0; k < 192; k++) acc += hS[qq][k] * w2S[o][k];
  const int q = q0 + qq;
  const int b = q / 1000, node = q - b * 1000;
  out[(size_t)b * 12000 + o * 1000 + node] = acc;
}

// ============================================================
extern "C" void kernel_launch(void* const* d_in, const int* in_sizes, int n_in,
                              void* d_out, int out_size, void* d_ws, size_t ws_size,
                              hipStream_t stream)
{
  const float* x     = (const float*)d_in[0];
  const float* A     = (const float*)d_in[1];
  const float* FSP   = (const float*)d_in[2];
  const float* DSP   = (const float*)d_in[3];
  const float* E1    = (const float*)d_in[4];
  const float* E2    = (const float*)d_in[5];
  const float* fus_W = (const float*)d_in[6];
  const float* fus_b = (const float*)d_in[7];
  const float* fus_v = (const float*)d_in[8];
  const float* beta1 = (const float*)d_in[9];
  const float* beta2 = (const float*)d_in[10];
  const float* gcn_W1= (const float*)d_in[11];
  const float* gcn_b1= (const float*)d_in[12];
  const float* ln1g  = (const float*)d_in[13];
  const float* ln1b  = (const float*)d_in[14];
  const float* gcn_W2= (const float*)d_in[15];
  const float* gcn_b2= (const float*)d_in[16];
  const float* ln2g  = (const float*)d_in[17];
  const float* ln2b  = (const float*)d_in[18];
  const float* Wih0  = (const float*)d_in[19];
  const float* Whh0  = (const float*)d_in[20];
  const float* bih0  = (const float*)d_in[21];
  const float* bhh0  = (const float*)d_in[22];
  const float* Wih1  = (const float*)d_in[23];
  const float* Whh1  = (const float*)d_in[24];
  const float* bih1  = (const float*)d_in[25];
  const float* bhh1  = (const float*)d_in[26];
  const float* att_w = (const float*)d_in[27];
  const float* fc1W  = (const float*)d_in[28];
  const float* fc1b  = (const float*)d_in[29];
  const float* fc2W  = (const float*)d_in[30];
  const float* fc2b  = (const float*)d_in[31];
  float* out = (float*)d_out;

  char* w = (char*)d_ws;
  auto alloc = [&](size_t bytes) -> char* {
    char* p = w;
    w += (bytes + 255) & ~(size_t)255;
    return p;
  };

  float* consts  = (float*)alloc(8 * 4);
  float* scp     = (float*)alloc(3 * 4);
  float* alphap  = (float*)alloc(3 * 4);
  float* rowsums = (float*)alloc(3000 * 4);
  float* dinvp   = (float*)alloc(1000 * 4);
  u16*   Gbuf    = (u16*)alloc((size_t)3000000 * 2);
  u16*   Sbf     = (u16*)alloc((size_t)1024 * 1024 * 2);
  u16*   xbf     = (u16*)alloc((size_t)384000 * 2);
  u16*   fusWbf  = (u16*)alloc((size_t)32000 * 2);
  u16*   Wih0b   = (u16*)alloc((size_t)55296 * 2);
  u16*   Whh0b   = (u16*)alloc((size_t)110592 * 2);
  u16*   Wih1b   = (u16*)alloc((size_t)110592 * 2);
  u16*   Whh1b   = (u16*)alloc((size_t)110592 * 2);
  u16*   w1s     = (u16*)alloc((size_t)192 * 576 * 2);
  u16*   W2s     = (u16*)alloc((size_t)96 * 192 * 2);
  float4* cwpk   = (float4*)alloc((size_t)96 * 16);
  float* fusWT   = (float*)alloc((size_t)32000 * 4);
  float* yt      = (float*)alloc((size_t)384000 * 4);
  u16*   h2t     = (u16*)alloc((size_t)36864 * 1024 * 2);  // 75.5 MB; states/FC alias later
  u16*   Gg      = (u16*)alloc((size_t)36864000 * 2);      // 73.7 MB
  float* Nv      = (float*)alloc((size_t)6144000 * 4);
  float* Mb0     = (float*)alloc((size_t)32000 * 4);
  float* Mb1     = (float*)alloc((size_t)32000 * 4);
  float* Lb0     = (float*)alloc((size_t)32000 * 4);
  float* Lb1     = (float*)alloc((size_t)32000 * 4);
  float* sc0     = (float*)alloc((size_t)32000 * 4);
  float* sc1     = (float*)alloc((size_t)32000 * 4);
  float* sc2     = (float*)alloc((size_t)32000 * 4);

  // state buffers alias h2t region (dead after k_bigemm): h0 x2, h1 x3
  u16* h0s[2] = { h2t,                    h2t + (size_t)6144000 };
  u16* h1s[3] = { h2t + (size_t)12288000, h2t + (size_t)18432000, h2t + (size_t)24576000 };
  // FC-head aliases (h1s[2] read by k_ctxsplit before fc1 writes hfc — stream-ordered)
  u16*   ctxs = h2t;
  float* hfc  = (float*)(h2t + (size_t)18432000);

  k_prep<<<4250, 256, 0, stream>>>(x, fus_W, Wih0, Whh0, Wih1, Whh1, gcn_W1, gcn_b1,
                                   gcn_W2, ln1g, ln1b, fc1W,
                                   xbf, fusWbf, Wih0b, Whh0b, Wih1b, Whh1b, W2s, cwpk,
                                   scp, w1s, fusWT, h2t, sc0, sc1, sc2, consts);
  k_adjrow<<<1000, 256, 0, stream>>>(A, FSP, DSP, E1, E2, beta1, beta2,
                                     fusWT, fus_b, fus_v, Gbuf, rowsums, scp);
  k_alpha<<<1, 256, 0, stream>>>(scp, rowsums, alphap, dinvp);
  k_shat<<<4000, 256, 0, stream>>>(Gbuf, alphap, dinvp, Sbf);
  gemm_nt<0><<<dim3(6, 8), 256, 0, stream>>>(Sbf, 1024, xbf, 1000, yt, 384, 1000, 384, 1000, nullptr);
  k_h2gemm<<<3000, 256, 0, stream>>>(yt, cwpk, W2s, consts, h2t);
  // Gg = LN2( S @ h2t^T + b2 )  (73.7 GFLOP, BK=64, fused LN2)
  k_bigemm<<<3072, 256, 0, stream>>>(Sbf, h2t, gcn_b2, ln2g, ln2b, Gg);

  // ---- merged GRU: 13 launches; layer0(u)+fold(u-2) || layer1(u-1) ----
  GruArgs ga;
  ga.Gg = Gg; ga.Wih0 = Wih0b; ga.Whh0 = Whh0b; ga.Wih1 = Wih1b; ga.Whh1 = Whh1b;
  ga.bih0 = bih0; ga.bhh0 = bhh0; ga.bih1 = bih1; ga.bhh1 = bhh1; ga.att_w = att_w;
  ga.h0[0] = h0s[0]; ga.h0[1] = h0s[1];
  ga.h1[0] = h1s[0]; ga.h1[1] = h1s[1]; ga.h1[2] = h1s[2];
  ga.M[0] = Mb0; ga.M[1] = Mb1; ga.L[0] = Lb0; ga.L[1] = Lb1;
  ga.s[0] = sc0; ga.s[1] = sc1; ga.s[2] = sc2;
  ga.Nv = Nv;
  for (int u = 0; u <= 12; ++u)
    k_gru2<<<dim3(12, 250), 256, 0, stream>>>(ga, u);

  // FC head: ctxsplit with fused final pool (tp=11: h1s[2], sc2, Mb0/Lb0)
  k_ctxsplit<<<24000, 256, 0, stream>>>(Nv, h1s[2], sc2, Mb0, Lb0, ctxs);
  gemm_nt<3><<<dim3(3, 250), 256, 0, stream>>>(ctxs, 576, w1s, 576, hfc, 192, 32000, 192, 576, fc1b);
  k_fc2<<<2000, 192, 0, stream>>>(hfc, fc2W, fc2b, out);
}

// Round 15
// 1422.415 us; speedup vs baseline: 3.2695x; 1.0019x over previous
//
#include <hip/hip_runtime.h>

typedef unsigned short u16;
typedef unsigned int u32;
typedef __attribute__((ext_vector_type(8))) short short8;   // 8 x bf16 (4 VGPRs)
typedef __attribute__((ext_vector_type(4))) float float4v;  // 4 x f32

#define DEV static __device__ __forceinline__

DEV float bf2f(u16 u) { u32 x = ((u32)u) << 16; float f; __builtin_memcpy(&f, &x, 4); return f; }
DEV u16 f2bf(float f) {
  u32 u; __builtin_memcpy(&u, &f, 4);
  u = (u + 0x7fffu + ((u >> 16) & 1u)) >> 16;
  return (u16)u;
}
DEV float sigm(float x) { return 1.f / (1.f + __expf(-x)); }

// async global->LDS, 16B per lane; LDS dest = wave-uniform base + lane*16
DEV void gl16(const u16* g, u16* l) {
  __builtin_amdgcn_global_load_lds(
      (const __attribute__((address_space(1))) void*)g,
      (__attribute__((address_space(3))) void*)l, 16, 0, 0);
}

// ============================================================
// Generic GEMM (small cases): C[M,N] = A[M,K](bf16) * B[N,K](bf16 "NK")
// OMODE: 0 = f32 row-major, 3 = f32 + bias + tanh-GELU epilogue (fc1)
// ============================================================
template <int OMODE>
__launch_bounds__(256)
__global__ void gemm_nt(const u16* __restrict__ A, int lda,
                        const u16* __restrict__ B, int ldb,
                        void* __restrict__ Cp, int ldc,
                        int M, int N, int K,
                        const float* __restrict__ bias)
{
  constexpr int PK = 40;
  __shared__ u16 As[128 * PK];
  __shared__ u16 Bs[64 * PK];

  const int tid  = threadIdx.x;
  const int m0   = blockIdx.y * 128;
  const int n0   = blockIdx.x * 64;
  const int wid  = tid >> 6;
  const int lane = tid & 63;
  const int l15  = lane & 15;
  const int quad = lane >> 4;
  const int wm   = (wid >> 1) * 64;
  const int wn   = (wid & 1) * 32;

  float4v acc[4][2];
  const float4v fz = {0.f, 0.f, 0.f, 0.f};
#pragma unroll
  for (int i = 0; i < 4; i++)
#pragma unroll
    for (int j = 0; j < 2; j++) acc[i][j] = fz;

  const int arow = tid >> 2;
  const int akc  = tid & 3;

  const int kt_count = (K + 31) / 32;
  for (int kt = 0; kt < kt_count; ++kt) {
    const int k0 = kt * 32 + akc * 8;
    const bool kok = (k0 < K);
    uint4 av0 = make_uint4(0, 0, 0, 0), av1 = av0, bv = av0;
    int ra = m0 + arow;
    if (kok && ra < M)        av0 = *(const uint4*)(A + (size_t)ra * lda + k0);
    if (kok && ra + 64 < M)   av1 = *(const uint4*)(A + (size_t)(ra + 64) * lda + k0);
    int rb = n0 + arow;
    if (kok && rb < N)        bv  = *(const uint4*)(B + (size_t)rb * ldb + k0);

    __syncthreads();
    *(uint4*)&As[arow * PK + akc * 8]        = av0;
    *(uint4*)&As[(arow + 64) * PK + akc * 8] = av1;
    *(uint4*)&Bs[arow * PK + akc * 8]        = bv;
    __syncthreads();

    short8 af[4], bfr[2];
#pragma unroll
    for (int i = 0; i < 4; i++)
      af[i] = *(const short8*)&As[(wm + i * 16 + l15) * PK + quad * 8];
#pragma unroll
    for (int j = 0; j < 2; j++)
      bfr[j] = *(const short8*)&Bs[(wn + j * 16 + l15) * PK + quad * 8];
#pragma unroll
    for (int i = 0; i < 4; i++)
#pragma unroll
      for (int j = 0; j < 2; j++)
        acc[i][j] = __builtin_amdgcn_mfma_f32_16x16x32_bf16(af[i], bfr[j], acc[i][j], 0, 0, 0);
  }

#pragma unroll
  for (int i = 0; i < 4; i++)
#pragma unroll
    for (int j = 0; j < 2; j++)
#pragma unroll
      for (int e = 0; e < 4; e++) {
        int r = m0 + wm + i * 16 + quad * 4 + e;
        int c = n0 + wn + j * 16 + l15;
        if (r < M && c < N) {
          float v = acc[i][j][e];
          if (OMODE == 0) ((float*)Cp)[(size_t)r * ldc + c] = v;
          else {
            float a = v + bias[c];
            float t = tanhf(0.7978845608028654f * (a + 0.044715f * a * a * a));
            ((float*)Cp)[(size_t)r * ldc + c] = 0.5f * a * (1.f + t);
          }
        }
      }
}

// ============================================================
// Big graph-conv GEMM + fused LN2: 128x192 tile (two complete channel
// groups per block; wave-column owns one group -> wave-local LN2 stats,
// no LDS exchange). BK=64, gl16, XOR swizzle, XCD swizzle.
// ============================================================
__launch_bounds__(256)
__global__ void k_bigemm(const u16* __restrict__ A,    // Sbf 1024x1024
                         const u16* __restrict__ B,    // h2t 36864x1024
                         const float* __restrict__ b2, const float* __restrict__ g2,
                         const float* __restrict__ be2,
                         u16* __restrict__ Gg)
{
  __shared__ u16 As[128 * 64];   // 16 KB
  __shared__ u16 Bs[192 * 64];   // 24 KB

  const int tid  = threadIdx.x;
  const int bid  = blockIdx.x;
  const int xcd  = bid & 7;
  const int jj   = bid >> 3;           // 0..191
  const int m0   = (jj & 7) * 128;
  const int rt2  = xcd + 8 * (jj >> 3);   // 0..191, two channel groups each

  const int wid  = tid >> 6;
  const int lane = tid & 63;
  const int l15  = lane & 15;
  const int quad = lane >> 4;
  const int wm   = (wid >> 1) * 64;
  const int wn   = (wid & 1) * 96;
  const int wni  = wid & 1;

  const int srow8 = lane >> 3;
  const int sw8   = ((lane & 7) ^ srow8) * 8;

  const u16* abase = A + (size_t)(m0 + wid * 8 + srow8) * 1024 + sw8;
  const u16* bbase = B + (size_t)(rt2 * 192 + wid * 8 + srow8) * 1024 + sw8;

  float4v acc[4][6];
  const float4v fz = {0.f, 0.f, 0.f, 0.f};
#pragma unroll
  for (int i = 0; i < 4; i++)
#pragma unroll
    for (int j = 0; j < 6; j++) acc[i][j] = fz;

  for (int kt = 0; kt < 16; ++kt) {
    const int ko = kt * 64;
#pragma unroll
    for (int c = 0; c < 4; c++)
      gl16(abase + (size_t)c * 32 * 1024 + ko, &As[(c * 32 + wid * 8) * 64]);
#pragma unroll
    for (int c = 0; c < 6; c++)
      gl16(bbase + (size_t)c * 32 * 1024 + ko, &Bs[(c * 32 + wid * 8) * 64]);
    __syncthreads();
#pragma unroll
    for (int k32 = 0; k32 < 2; k32++) {
      const int swr = ((quad + 4 * k32) ^ (l15 & 7)) * 8;
      short8 af[4], bf[6];
#pragma unroll
      for (int i = 0; i < 4; i++)
        af[i] = *(const short8*)&As[(wm + i * 16 + l15) * 64 + swr];
#pragma unroll
      for (int j = 0; j < 6; j++)
        bf[j] = *(const short8*)&Bs[(wn + j * 16 + l15) * 64 + swr];
#pragma unroll
      for (int i = 0; i < 4; i++)
#pragma unroll
        for (int j = 0; j < 6; j++)
          acc[i][j] = __builtin_amdgcn_mfma_f32_16x16x32_bf16(af[i], bf[j], acc[i][j], 0, 0, 0);
    }
    __syncthreads();
  }

  // ---- wave-local LN2 epilogue: wave-column wni owns channel group rs ----
  const int rs = rt2 * 2 + wni;
  float b2v[6], g2v[6], bev[6];
#pragma unroll
  for (int j = 0; j < 6; j++) {
    int cc = j * 16 + l15;            // 0..95 within the group
    b2v[j] = b2[cc]; g2v[j] = g2[cc]; bev[j] = be2[cc];
  }
#pragma unroll
  for (int i = 0; i < 4; i++)
#pragma unroll
    for (int e = 0; e < 4; e++) {
      float s = 0.f, ss = 0.f;
#pragma unroll
      for (int j = 0; j < 6; j++) {
        float v = acc[i][j][e] + b2v[j];
        acc[i][j][e] = v;
        s += v; ss += v * v;
      }
      s += __shfl_xor(s, 1); ss += __shfl_xor(ss, 1);
      s += __shfl_xor(s, 2); ss += __shfl_xor(ss, 2);
      s += __shfl_xor(s, 4); ss += __shfl_xor(ss, 4);
      s += __shfl_xor(s, 8); ss += __shfl_xor(ss, 8);
      const int m = m0 + wm + i * 16 + quad * 4 + e;
      if (m < 1000) {
        float mean = s * (1.f / 96.f);
        float var  = ss * (1.f / 96.f) - mean * mean;
        float isd  = rsqrtf(var + 1e-5f);
#pragma unroll
        for (int j = 0; j < 6; j++) {
          int cc = j * 16 + l15;
          Gg[(size_t)rs * 96000 + (size_t)m * 96 + cc] =
              f2bf((acc[i][j][e] - mean) * isd * g2v[j] + bev[j]);
        }
      }
    }
}

// ============================================================
// Online-softmax pool fold for timestep tp (tile m0/c0 owns 128q x 32c).
// pm: 1 = init (tp==0), 2 = normal.
// ============================================================
DEV void pool_fold(int m0, int c0, int pm,
                   const u16* __restrict__ Hpool,
                   const float* __restrict__ score_rd,
                   const float* __restrict__ Mrd, const float* __restrict__ Lrd,
                   float* __restrict__ Mwr, float* __restrict__ Lwr,
                   float* __restrict__ Nvp)
{
  const int tid = threadIdx.x;
#pragma unroll
  for (int k = 0; k < 16; k++) {
    int idx = k * 256 + tid;
    int ql = idx >> 5, cl = idx & 31;
    int q = m0 + ql, c = c0 + cl;
    size_t nidx = (size_t)q * 192 + c;
    float s = score_rd[q];
    float hnew = bf2f(Hpool[nidx]);
    float so, wnf, prev;
    if (pm == 1) { so = 0.f; wnf = 1.f; prev = 0.f; }
    else {
      float Mo = Mrd[q];
      float Mn = fmaxf(Mo, s);
      so = __expf(Mo - Mn); wnf = __expf(s - Mn);
      prev = Nvp[nidx];
    }
    Nvp[nidx] = prev * so + wnf * hnew;
  }
  if (c0 == 0 && tid < 128) {
    int q = m0 + tid;
    float s = score_rd[q];
    if (pm == 1) { Mwr[q] = s; Lwr[q] = 1.f; }
    else {
      float Mo = Mrd[q], Mn = fmaxf(Mo, s);
      Mwr[q] = Mn;
      Lwr[q] = Lrd[q] * __expf(Mo - Mn) + __expf(s - Mn);
    }
  }
}

// ============================================================
// GRU tile device function. BM=128, 32 cols/gate.
// K=192 phases BK=64; K=96 X-phase BK=32. XOR-swizzled LDS.
// ============================================================
template <int KX, bool POOL>
DEV void gru_tile(u16* As, u16* Bs,
                  int m0, int c0,
                  const u16* __restrict__ Xin, int ldx,
                  const u16* __restrict__ Win,
                  const u16* __restrict__ Hin,
                  const u16* __restrict__ Whh,
                  const float* __restrict__ bih, const float* __restrict__ bhh,
                  u16* __restrict__ Hout,
                  const float* __restrict__ att_w,
                  float* __restrict__ score_acc,
                  const u16* __restrict__ Hpool,
                  const float* __restrict__ score_rd,
                  const float* __restrict__ Mrd, const float* __restrict__ Lrd,
                  float* __restrict__ Mwr, float* __restrict__ Lwr,
                  float* __restrict__ Nvp,
                  int t0, int pm)
{
  const int tid  = threadIdx.x;
  const int wid  = tid >> 6;
  const int lane = tid & 63;
  const int l15  = lane & 15;
  const int quad = lane >> 4;
  const int wm   = wid * 32;

  // ---- folded pool (layer0 part, timestep u-2) ----
  if (!POOL && pm)
    pool_fold(m0, c0, pm, Hpool, score_rd, Mrd, Lrd, Mwr, Lwr, Nvp);

  const int srow8 = lane >> 3;
  const int sw8   = ((lane & 7) ^ srow8) * 8;
  const int srow4 = lane >> 2;
  const int sw4   = ((lane & 3) ^ ((lane >> 3) & 3)) * 8;

  float4v aR[2][2], aZ[2][2], aXN[2][2], aHN[2][2];
  const float4v fz = {0.f, 0.f, 0.f, 0.f};
#pragma unroll
  for (int i = 0; i < 2; i++)
#pragma unroll
    for (int j = 0; j < 2; j++) { aR[i][j] = fz; aZ[i][j] = fz; aXN[i][j] = fz; aHN[i][j] = fz; }

  // ---- phase X ----
  if (KX == 96) {
    const u16* ax0 = Xin + (size_t)(m0 + wid * 16 + srow4) * ldx + sw4;
    const u16* ax1 = Xin + (size_t)(m0 + 64 + wid * 16 + srow4) * ldx + sw4;
    const int b0 = wid * 16 + srow4;
    const u16* bx0 = Win + (size_t)((b0 >> 5) * 192 + c0 + (b0 & 31)) * 96 + sw4;
    const int b1 = 64 + wid * 16 + srow4;
    const u16* bx1 = Win + (size_t)(384 + c0 + (b1 & 31)) * 96 + sw4;
    u16* asl0 = &As[(wid * 16) * 32];
    u16* asl1 = &As[(64 + wid * 16) * 32];
    u16* bsl0 = &Bs[(wid * 16) * 32];
    u16* bsl1 = &Bs[(64 + wid * 16) * 32];
    const int swa = (quad ^ ((l15 >> 1) & 3)) * 8;
#pragma unroll
    for (int kt = 0; kt < 3; ++kt) {
      const int ko = kt * 32;
      gl16(ax0 + ko, asl0); gl16(ax1 + ko, asl1);
      gl16(bx0 + ko, bsl0);
      if (wid < 2) gl16(bx1 + ko, bsl1);
      __syncthreads();
      short8 af[2], bR[2], bZ[2], bN[2];
#pragma unroll
      for (int i = 0; i < 2; i++)
        af[i] = *(const short8*)&As[(wm + i * 16 + l15) * 32 + swa];
#pragma unroll
      for (int j = 0; j < 2; j++) {
        bR[j] = *(const short8*)&Bs[(j * 16 + l15) * 32 + swa];
        bZ[j] = *(const short8*)&Bs[(32 + j * 16 + l15) * 32 + swa];
        bN[j] = *(const short8*)&Bs[(64 + j * 16 + l15) * 32 + swa];
      }
#pragma unroll
      for (int i = 0; i < 2; i++)
#pragma unroll
        for (int j = 0; j < 2; j++) {
          aR[i][j]  = __builtin_amdgcn_mfma_f32_16x16x32_bf16(af[i], bR[j], aR[i][j], 0, 0, 0);
          aZ[i][j]  = __builtin_amdgcn_mfma_f32_16x16x32_bf16(af[i], bZ[j], aZ[i][j], 0, 0, 0);
          aXN[i][j] = __builtin_amdgcn_mfma_f32_16x16x32_bf16(af[i], bN[j], aXN[i][j], 0, 0, 0);
        }
      __syncthreads();
    }
  } else {
    const u16* abase = Xin + (size_t)(m0 + wid * 8 + srow8) * 192 + sw8;
    const u16* bbase = Win + (size_t)(c0 + wid * 8 + srow8) * 192 + sw8;
#pragma unroll
    for (int kt = 0; kt < 3; ++kt) {
      const int ko = kt * 64;
#pragma unroll
      for (int c = 0; c < 4; c++)
        gl16(abase + (size_t)c * 32 * 192 + ko, &As[(c * 32 + wid * 8) * 64]);
#pragma unroll
      for (int c = 0; c < 3; c++)
        gl16(bbase + (size_t)c * 192 * 192 + ko, &Bs[(c * 32 + wid * 8) * 64]);
      __syncthreads();
#pragma unroll
      for (int k32 = 0; k32 < 2; k32++) {
        const int swr = ((quad + 4 * k32) ^ (l15 & 7)) * 8;
        short8 af[2], bR[2], bZ[2], bN[2];
#pragma unroll
        for (int i = 0; i < 2; i++)
          af[i] = *(const short8*)&As[(wm + i * 16 + l15) * 64 + swr];
#pragma unroll
        for (int j = 0; j < 2; j++) {
          bR[j] = *(const short8*)&Bs[(j * 16 + l15) * 64 + swr];
          bZ[j] = *(const short8*)&Bs[(32 + j * 16 + l15) * 64 + swr];
          bN[j] = *(const short8*)&Bs[(64 + j * 16 + l15) * 64 + swr];
        }
#pragma unroll
        for (int i = 0; i < 2; i++)
#pragma unroll
          for (int j = 0; j < 2; j++) {
            aR[i][j]  = __builtin_amdgcn_mfma_f32_16x16x32_bf16(af[i], bR[j], aR[i][j], 0, 0, 0);
            aZ[i][j]  = __builtin_amdgcn_mfma_f32_16x16x32_bf16(af[i], bZ[j], aZ[i][j], 0, 0, 0);
            aXN[i][j] = __builtin_amdgcn_mfma_f32_16x16x32_bf16(af[i], bN[j], aXN[i][j], 0, 0, 0);
          }
      }
      __syncthreads();
    }
  }
  // ---- phase H: K=192, BK=64 x 3 ----
  if (!t0) {
    const u16* abase = Hin + (size_t)(m0 + wid * 8 + srow8) * 192 + sw8;
    const u16* bbase = Whh + (size_t)(c0 + wid * 8 + srow8) * 192 + sw8;
#pragma unroll
    for (int kt = 0; kt < 3; ++kt) {
      const int ko = kt * 64;
#pragma unroll
      for (int c = 0; c < 4; c++)
        gl16(abase + (size_t)c * 32 * 192 + ko, &As[(c * 32 + wid * 8) * 64]);
#pragma unroll
      for (int c = 0; c < 3; c++)
        gl16(bbase + (size_t)c * 192 * 192 + ko, &Bs[(c * 32 + wid * 8) * 64]);
      __syncthreads();
#pragma unroll
      for (int k32 = 0; k32 < 2; k32++) {
        const int swr = ((quad + 4 * k32) ^ (l15 & 7)) * 8;
        short8 af[2], bR[2], bZ[2], bN[2];
#pragma unroll
        for (int i = 0; i < 2; i++)
          af[i] = *(const short8*)&As[(wm + i * 16 + l15) * 64 + swr];
#pragma unroll
        for (int j = 0; j < 2; j++) {
          bR[j] = *(const short8*)&Bs[(j * 16 + l15) * 64 + swr];
          bZ[j] = *(const short8*)&Bs[(32 + j * 16 + l15) * 64 + swr];
          bN[j] = *(const short8*)&Bs[(64 + j * 16 + l15) * 64 + swr];
        }
#pragma unroll
        for (int i = 0; i < 2; i++)
#pragma unroll
          for (int j = 0; j < 2; j++) {
            aR[i][j]  = __builtin_amdgcn_mfma_f32_16x16x32_bf16(af[i], bR[j], aR[i][j], 0, 0, 0);
            aZ[i][j]  = __builtin_amdgcn_mfma_f32_16x16x32_bf16(af[i], bZ[j], aZ[i][j], 0, 0, 0);
            aHN[i][j] = __builtin_amdgcn_mfma_f32_16x16x32_bf16(af[i], bN[j], aHN[i][j], 0, 0, 0);
          }
      }
      __syncthreads();
    }
  }

  // ---- epilogue: gates + state write (+ pooling partials) ----
  float ps[2][4];
  if (POOL) {
#pragma unroll
    for (int i = 0; i < 2; i++)
#pragma unroll
      for (int e = 0; e < 4; e++) ps[i][e] = 0.f;
  }
#pragma unroll
  for (int j = 0; j < 2; ++j) {
    const int c = c0 + j * 16 + l15;
    const float brz = bih[c] + bhh[c];
    const float bzz = bih[192 + c] + bhh[192 + c];
    const float bxn = bih[384 + c];
    const float bhn = bhh[384 + c];
    const float aw  = POOL ? att_w[c] : 0.f;
#pragma unroll
    for (int i = 0; i < 2; ++i)
#pragma unroll
      for (int e = 0; e < 4; ++e) {
        const int row = m0 + wm + i * 16 + quad * 4 + e;
        float rg  = sigm(aR[i][j][e] + brz);
        float zg  = sigm(aZ[i][j][e] + bzz);
        float hnv = bhn + (t0 ? 0.f : aHN[i][j][e]);
        float ng  = tanhf(aXN[i][j][e] + bxn + rg * hnv);
        float hold = t0 ? 0.f : bf2f(Hin[(size_t)row * 192 + c]);
        float hnew = (1.f - zg) * ng + zg * hold;
        Hout[(size_t)row * 192 + c] = f2bf(hnew);
        if (POOL) ps[i][e] += hnew * aw;
      }
  }
  if (POOL) {
#pragma unroll
    for (int i = 0; i < 2; ++i)
#pragma unroll
      for (int e = 0; e < 4; ++e) {
        float v = ps[i][e];
        v += __shfl_xor(v, 1); v += __shfl_xor(v, 2);
        v += __shfl_xor(v, 4); v += __shfl_xor(v, 8);
        if (l15 == 0) atomicAdd(&score_acc[m0 + wm + i * 16 + quad * 4 + e], v);
      }
  }
}

// ============================================================
// Merged GRU launch u (0..12): x<6 -> layer0(step u) + fold(u-2),
// x>=6 -> layer1(step u-1). At u=12 the layer0 branch is fold-only (tp=10).
// ============================================================
struct GruArgs {
  const u16 *Gg, *Wih0, *Whh0, *Wih1, *Whh1;
  const float *bih0, *bhh0, *bih1, *bhh1, *att_w;
  u16 *h0[2];
  u16 *h1[3];
  float *M[2], *L[2], *s[3];
  float* Nv;
};

__launch_bounds__(256)
__global__ void k_gru2(GruArgs a, int u)
{
  __shared__ u16 As[128 * 64];
  __shared__ u16 Bs[96 * 64];
  const int m0 = blockIdx.y * 128;

  if (blockIdx.x < 6) {
    const int c0 = blockIdx.x * 32;
    const int pm = (u < 2) ? 0 : (u == 2 ? 1 : 2);
    if (u > 11) {
      if (pm)
        pool_fold(m0, c0, pm, a.h1[(u + 1) % 3], a.s[(u + 1) % 3],
                  a.M[(u + 1) & 1], a.L[(u + 1) & 1], a.M[u & 1], a.L[u & 1], a.Nv);
      return;
    }
    if (c0 == 0 && threadIdx.x < 128) a.s[u % 3][m0 + threadIdx.x] = 0.f;
    gru_tile<96, false>(As, Bs, m0, c0,
        a.Gg + u * 96, 1152, a.Wih0, a.h0[u & 1], a.Whh0, a.bih0, a.bhh0, a.h0[(u & 1) ^ 1],
        nullptr, nullptr,
        a.h1[(u + 1) % 3], a.s[(u + 1) % 3],
        a.M[(u + 1) & 1], a.L[(u + 1) & 1],
        a.M[u & 1], a.L[u & 1],
        a.Nv, u == 0, pm);
  } else {
    if (u < 1) return;
    const int t = u - 1;
    const int c0 = (blockIdx.x - 6) * 32;
    gru_tile<192, true>(As, Bs, m0, c0,
        a.h0[u & 1], 192, a.Wih1, a.h1[(u + 1) % 3], a.Whh1, a.bih1, a.bhh1, a.h1[t % 3],
        a.att_w, a.s[t % 3],
        nullptr, nullptr, nullptr, nullptr, nullptr, nullptr, nullptr,
        t == 0, 0);
  }
}

// ============================================================
// H2 GEMM: h2t[(r*96+c2)*1024+n] = Hln @ W2 (analytic LN1 in A-staging)
// ============================================================
__launch_bounds__(256)
__global__ void k_h2gemm(const float* __restrict__ yt, const float4* __restrict__ cwpk,
                         const u16* __restrict__ W2s, const float* __restrict__ consts,
                         u16* __restrict__ h2t)
{
  constexpr int PK = 40;
  __shared__ u16 As[128 * PK];
  __shared__ u16 Bs[96 * PK];
  __shared__ u16 Ts[96 * 136];

  const int tid  = threadIdx.x;
  const int m0   = blockIdx.x * 128;
  const int wid  = tid >> 6;
  const int lane = tid & 63;
  const int l15  = lane & 15;
  const int quad = lane >> 4;
  const int wm   = (wid >> 1) * 64;
  const int wn   = (wid & 1) * 48;

  const float P = consts[0], Q = consts[1], VW = consts[2], CWB = consts[3], VB = consts[4];

  const int arow = tid >> 2;
  const int akc  = tid & 3;

  float yv[2], mu[2], iv[2];
#pragma unroll
  for (int rr = 0; rr < 2; rr++) {
    int i = m0 + arow + rr * 64;
    int r = i / 1000, n = i - r * 1000;
    float y = yt[n * 384 + r];
    yv[rr] = y;
    mu[rr] = y * P + Q;
    iv[rr] = rsqrtf(y * y * VW + 2.f * y * CWB + VB + 1e-5f);
  }

  float4v acc[4][3];
  const float4v fz = {0.f, 0.f, 0.f, 0.f};
#pragma unroll
  for (int i = 0; i < 4; i++)
#pragma unroll
    for (int j = 0; j < 3; j++) acc[i][j] = fz;

  uint4 asave[2][3];
  const bool has2 = (arow < 32);

  for (int kt = 0; kt < 6; ++kt) {
    const int k0 = kt * 32 + akc * 8;
    uint4 av[2];
    if (kt < 3) {
#pragma unroll
      for (int rr = 0; rr < 2; rr++) {
        u16 hb[8];
#pragma unroll
        for (int e = 0; e < 8; e++) {
          float4 cw = cwpk[k0 + e];
          float t = yv[rr] * cw.x + cw.y - mu[rr];
          float h = fmaxf(t * iv[rr] * cw.z + cw.w, 0.f);
          hb[e] = f2bf(h);
        }
        __builtin_memcpy(&av[rr], hb, 16);
        asave[rr][kt] = av[rr];
      }
    } else {
      av[0] = asave[0][kt - 3];
      av[1] = asave[1][kt - 3];
    }
    uint4 bv0 = *(const uint4*)(W2s + (size_t)arow * 192 + k0);
    uint4 bv1 = make_uint4(0, 0, 0, 0);
    if (has2) bv1 = *(const uint4*)(W2s + (size_t)(arow + 64) * 192 + k0);

    __syncthreads();
    *(uint4*)&As[arow * PK + akc * 8]        = av[0];
    *(uint4*)&As[(arow + 64) * PK + akc * 8] = av[1];
    *(uint4*)&Bs[arow * PK + akc * 8]        = bv0;
    if (has2) *(uint4*)&Bs[(arow + 64) * PK + akc * 8] = bv1;
    __syncthreads();

    short8 af[4], bfr[3];
#pragma unroll
    for (int i = 0; i < 4; i++)
      af[i] = *(const short8*)&As[(wm + i * 16 + l15) * PK + quad * 8];
#pragma unroll
    for (int j = 0; j < 3; j++)
      bfr[j] = *(const short8*)&Bs[(wn + j * 16 + l15) * PK + quad * 8];
#pragma unroll
    for (int i = 0; i < 4; i++)
#pragma unroll
      for (int j = 0; j < 3; j++)
        acc[i][j] = __builtin_amdgcn_mfma_f32_16x16x32_bf16(af[i], bfr[j], acc[i][j], 0, 0, 0);
  }

#pragma unroll
  for (int i = 0; i < 4; i++)
#pragma unroll
    for (int j = 0; j < 3; j++)
#pragma unroll
      for (int e = 0; e < 4; e++) {
        int rowl = wm + i * 16 + quad * 4 + e;
        int c2   = wn + j * 16 + l15;
        Ts[c2 * 136 + rowl] = f2bf(acc[i][j][e]);
      }
  __syncthreads();
#pragma unroll
  for (int u = tid; u < 1536; u += 256) {
    int c2 = u >> 4, ch = u & 15;
    int iidx0 = m0 + ch * 8;
    int r = iidx0 / 1000, n0 = iidx0 - r * 1000;
    *(uint4*)(h2t + (size_t)(r * 96 + c2) * 1024 + n0) = *(const uint4*)&Ts[c2 * 136 + ch * 8];
  }
}

// ============================================================
// prep: all f32->bf16 conversions, W1/b1 moments, W2 split, cw pack,
// fc1W split, fusW transpose (f32), h2t K-pad zero, score/sc zero.
// ============================================================
__launch_bounds__(256)
__global__ void k_prep(const float* x, const float* fus_W,
                       const float* Wih0, const float* Whh0,
                       const float* Wih1, const float* Whh1,
                       const float* gcn_W1, const float* gcn_b1,
                       const float* gcn_W2, const float* ln1g, const float* ln1b,
                       const float* fc1W,
                       u16* xbf, u16* fusWbf, u16* Wih0b, u16* Whh0b, u16* Wih1b, u16* Whh1b,
                       u16* W2s, float4* cwpk, float* scp, u16* w1s, float* fusWT,
                       u16* h2t, float* s0, float* s1, float* s2, float* consts)
{
  long o = (long)blockIdx.x * 256 + threadIdx.x;
  if (o < 384000) xbf[o] = f2bf(x[o]);
  else if ((o -= 384000) < 32000) fusWbf[o] = f2bf(fus_W[o]);
  else if ((o -= 32000) < 55296)  Wih0b[o] = f2bf(Wih0[o]);
  else if ((o -= 55296) < 110592) Whh0b[o] = f2bf(Whh0[o]);
  else if ((o -= 110592) < 110592) Wih1b[o] = f2bf(Wih1[o]);
  else if ((o -= 110592) < 110592) Whh1b[o] = f2bf(Whh1[o]);
  else if ((o -= 110592) < 9216) {
    int c2 = (int)o / 96, c = (int)o - c2 * 96;
    float wv = gcn_W2[c * 96 + c2];
    u16 hi = f2bf(wv);
    u16 lo = f2bf(wv - bf2f(hi));
    W2s[c2 * 192 + c] = hi;
    W2s[c2 * 192 + 96 + c] = lo;
  }
  else if ((o -= 9216) < 96) {
    int c = (int)o;
    float4 cw;
    cw.x = gcn_W1[c]; cw.y = gcn_b1[c]; cw.z = ln1g[c]; cw.w = ln1b[c];
    cwpk[c] = cw;
  }
  else if ((o -= 96) < 3) scp[o] = 0.f;
  else if ((o -= 3) < 36864) {
    int n = (int)o / 192, k = (int)o - n * 192;
    float wv = fc1W[o];
    u16 hi = f2bf(wv);
    u16 lo = f2bf(wv - bf2f(hi));
    w1s[(size_t)n * 576 + k]       = hi;
    w1s[(size_t)n * 576 + 192 + k] = lo;
    w1s[(size_t)n * 576 + 384 + k] = hi;
  }
  else if ((o -= 36864) < 32000) {
    int m = (int)o >> 5, a = (int)o & 31;
    fusWT[o] = fus_W[a * 1000 + m];
  }
  else if ((o -= 32000) < 110592) {
    int row = (int)o / 3, p = (int)o - row * 3;
    *(uint4*)(h2t + (size_t)row * 1024 + 1000 + p * 8) = make_uint4(0, 0, 0, 0);
  }
  else if ((o -= 110592) < 96000) {
    if (o < 32000) s0[o] = 0.f;
    else if (o < 64000) s1[o - 32000] = 0.f;
    else s2[o - 64000] = 0.f;
  }
  if (blockIdx.x == 0 && threadIdx.x == 0) {
    float sw = 0, sb = 0, sww = 0, swb = 0, sbb = 0;
    for (int c = 0; c < 96; c++) {
      float wv = gcn_W1[c], b = gcn_b1[c];
      sw += wv; sb += b; sww += wv * wv; swb += wv * b; sbb += b * b;
    }
    float P = sw / 96.f, Q = sb / 96.f;
    consts[0] = P; consts[1] = Q;
    consts[2] = sww / 96.f - P * P;
    consts[3] = swb / 96.f - P * Q;
    consts[4] = sbb / 96.f - Q * Q;
  }
}

// ============================================================
// per-row: Aadp softmax + 3 candidate graphs + row sums + fused
// P = G @ fusW^T and sc contribution (atomicAdd into scp).
// ============================================================
__launch_bounds__(256)
__global__ void k_adjrow(const float* __restrict__ A, const float* __restrict__ FSP,
                         const float* __restrict__ DSP, const float* __restrict__ E1,
                         const float* __restrict__ E2,
                         const float* beta1, const float* beta2,
                         const float* __restrict__ fusWT,
                         const float* __restrict__ fus_b, const float* __restrict__ fus_v,
                         u16* __restrict__ G, float* __restrict__ rowsums,
                         float* __restrict__ scp)
{
  __shared__ float z[1000];
  __shared__ float red[256];
  __shared__ float gk[3000];
  __shared__ float pred[768];     // [k*256 + a*8 + grp]
  __shared__ float vred[96];
  const int n = blockIdx.x, tid = threadIdx.x;

  float e1r[10];
#pragma unroll
  for (int d = 0; d < 10; d++) e1r[d] = E1[n * 10 + d];

  float lmax = -1e30f;
  for (int m = tid; m < 1000; m += 256) {
    float s = 0;
#pragma unroll
    for (int d = 0; d < 10; d++) s += e1r[d] * E2[m * 10 + d];
    s = fmaxf(s, 0.f);
    z[m] = s;
    lmax = fmaxf(lmax, s);
  }
  red[tid] = lmax; __syncthreads();
  for (int st = 128; st > 0; st >>= 1) { if (tid < st) red[tid] = fmaxf(red[tid], red[tid + st]); __syncthreads(); }
  const float mx = red[0]; __syncthreads();

  float lsum = 0;
  for (int m = tid; m < 1000; m += 256) { float e = __expf(z[m] - mx); z[m] = e; lsum += e; }
  red[tid] = lsum; __syncthreads();
  for (int st = 128; st > 0; st >>= 1) { if (tid < st) red[tid] += red[tid + st]; __syncthreads(); }
  const float inv = 1.f / red[0]; __syncthreads();

  const float w1 = sigm(beta1[0]);
  const float w2 = sigm(beta2[0]);
  float s0 = 0, s1 = 0, s2 = 0;
  for (int m = tid; m < 1000; m += 256) {
    float aadp = z[m] * inv;
    float a = A[n * 1000 + m], f = FSP[n * 1000 + m], dd = DSP[n * 1000 + m];
    float g0 = 0.5f * a + 0.5f * aadp;
    float g1 = w1 * a + (1.f - w1) * f;
    float g2 = w2 * a + (1.f - w2) * dd;
    G[0 * 1000000 + n * 1000 + m] = f2bf(g0);
    G[1 * 1000000 + n * 1000 + m] = f2bf(g1);
    G[2 * 1000000 + n * 1000 + m] = f2bf(g2);
    gk[m] = g0; gk[1000 + m] = g1; gk[2000 + m] = g2;
    s0 += g0; s1 += g1; s2 += g2;
  }
  red[tid] = s0; __syncthreads();
  for (int st = 128; st > 0; st >>= 1) { if (tid < st) red[tid] += red[tid + st]; __syncthreads(); }
  if (tid == 0) rowsums[n] = red[0];
  __syncthreads();
  red[tid] = s1; __syncthreads();
  for (int st = 128; st > 0; st >>= 1) { if (tid < st) red[tid] += red[tid + st]; __syncthreads(); }
  if (tid == 0) rowsums[1000 + n] = red[0];
  __syncthreads();
  red[tid] = s2; __syncthreads();
  for (int st = 128; st > 0; st >>= 1) { if (tid < st) red[tid] += red[tid + st]; __syncthreads(); }
  if (tid == 0) rowsums[2000 + n] = red[0];
  __syncthreads();

  // ---- fused P + sc: thread = (a, grp); P[k,a] = sum_m gk[m]*fusWT[m*32+a]
  const int a = tid & 31, grp = tid >> 5;
  float p0 = 0.f, p1 = 0.f, p2 = 0.f;
  for (int m = grp; m < 1000; m += 8) {
    float wv = fusWT[m * 32 + a];
    p0 += gk[m] * wv;
    p1 += gk[1000 + m] * wv;
    p2 += gk[2000 + m] * wv;
  }
  pred[0 * 256 + a * 8 + grp] = p0;
  pred[1 * 256 + a * 8 + grp] = p1;
  pred[2 * 256 + a * 8 + grp] = p2;
  __syncthreads();
  if (tid < 96) {
    int k = tid >> 5, aa = tid & 31;
    float P = 0.f;
#pragma unroll
    for (int g = 0; g < 8; g++) P += pred[k * 256 + aa * 8 + g];
    vred[k * 32 + aa] = tanhf(P + fus_b[aa]) * fus_v[aa];
  }
  __syncthreads();
  if (tid < 3) {
    float s = 0.f;
#pragma unroll
    for (int aa = 0; aa < 32; aa++) s += vred[tid * 32 + aa];
    atomicAdd(&scp[tid], s * 0.001f);
  }
}

// S_hat -> Sbf with 1024 K-pad stride; alpha/dinv computed inline
// (bit-identical to the old k_alpha formula; removes the 1-block launch)
__launch_bounds__(256)
__global__ void k_shat(const u16* __restrict__ G, const float* __restrict__ scp,
                       const float* __restrict__ rowsums, u16* __restrict__ S)
{
  int idx = blockIdx.x * 256 + threadIdx.x;
  if (idx >= 1024000) return;
  int i = idx >> 10, j = idx & 1023;
  u16 val = 0;
  const float sc0 = scp[0], sc1 = scp[1], sc2 = scp[2];
  const float mm = fmaxf(sc0, fmaxf(sc1, sc2));
  const float e0 = __expf(sc0 - mm), e1 = __expf(sc1 - mm), e2 = __expf(sc2 - mm);
  const float inv = 1.f / (e0 + e1 + e2);
  const float a0 = e0 * inv, a1 = e1 * inv, a2 = e2 * inv;
  if (j < 1000) {
    float di = rsqrtf(fmaxf(a0 * rowsums[i] + a1 * rowsums[1000 + i] + a2 * rowsums[2000 + i] + 1.0f, 1e-12f));
    float dj = rsqrtf(fmaxf(a0 * rowsums[j] + a1 * rowsums[1000 + j] + a2 * rowsums[2000 + j] + 1.0f, 1e-12f));
    int g = i * 1000 + j;
    float mg = a0 * bf2f(G[g]) + a1 * bf2f(G[1000000 + g]) + a2 * bf2f(G[2000000 + g]);
    if (i == j) mg += 1.0f;
    val = f2bf(mg * di * dj);
  }
  S[(size_t)i * 1024 + j] = val;
}

// ctx with fused final pool (tp=11): v = (Nv*so + wn*h)/L, split hi/lo bf16
__launch_bounds__(256)
__global__ void k_ctxsplit(const float* __restrict__ Nv, const u16* __restrict__ Hlast,
                           const float* __restrict__ score_rd,
                           const float* __restrict__ Mrd, const float* __restrict__ Lrd,
                           u16* __restrict__ ctxs)
{
  const int i = blockIdx.x * 256 + threadIdx.x;
  if (i >= 32000 * 192) return;
  const int q = i / 192, c = i - q * 192;
  const float s = score_rd[q];
  const float Mo = Mrd[q];
  const float Mn = fmaxf(Mo, s);
  const float so = __expf(Mo - Mn);
  const float wn = __expf(s - Mn);
  const float L = Lrd[q] * so + wn;
  float v = (Nv[i] * so + wn * bf2f(Hlast[i])) / L;
  u16 hi = f2bf(v);
  u16 lo = f2bf(v - bf2f(hi));
  u16* row = ctxs + (size_t)q * 576;
  row[c] = hi; row[192 + c] = hi; row[384 + c] = lo;
}

// fc2: LDS-staged tiny GEMM + transposed store
__launch_bounds__(192)
__global__ void k_fc2(const float* __restrict__ hfc, const float* __restrict__ fc2W,
                      const float* __restrict__ fc2b, float* __restrict__ out)
{
  __shared__ float w2S[12][193];
  __shared__ float hS[16][193];
  const int tid = threadIdx.x;
  const int q0 = blockIdx.x * 16;
  for (int idx = tid; idx < 12 * 192; idx += 192) {
    int o = idx / 192, k = idx - o * 192;
    w2S[o][k] = fc2W[idx];
  }
  for (int idx = tid; idx < 16 * 192; idx += 192) {
    int qq = idx / 192, k = idx - qq * 192;
    hS[qq][k] = hfc[(size_t)(q0 + qq) * 192 + k];
  }
  __syncthreads();
  const int qq = tid / 12, o = tid - qq * 12;
  float acc = fc2b[o];
#pragma unroll 8
  for (int k = 0; k < 192; k++) acc += hS[qq][k] * w2S[o][k];
  const int q = q0 + qq;
  const int b = q / 1000, node = q - b * 1000;
  out[(size_t)b * 12000 + o * 1000 + node] = acc;
}

// ============================================================
extern "C" void kernel_launch(void* const* d_in, const int* in_sizes, int n_in,
                              void* d_out, int out_size, void* d_ws, size_t ws_size,
                              hipStream_t stream)
{
  const float* x     = (const float*)d_in[0];
  const float* A     = (const float*)d_in[1];
  const float* FSP   = (const float*)d_in[2];
  const float* DSP   = (const float*)d_in[3];
  const float* E1    = (const float*)d_in[4];
  const float* E2    = (const float*)d_in[5];
  const float* fus_W = (const float*)d_in[6];
  const float* fus_b = (const float*)d_in[7];
  const float* fus_v = (const float*)d_in[8];
  const float* beta1 = (const float*)d_in[9];
  const float* beta2 = (const float*)d_in[10];
  const float* gcn_W1= (const float*)d_in[11];
  const float* gcn_b1= (const float*)d_in[12];
  const float* ln1g  = (const float*)d_in[13];
  const float* ln1b  = (const float*)d_in[14];
  const float* gcn_W2= (const float*)d_in[15];
  const float* gcn_b2= (const float*)d_in[16];
  const float* ln2g  = (const float*)d_in[17];
  const float* ln2b  = (const float*)d_in[18];
  const float* Wih0  = (const float*)d_in[19];
  const float* Whh0  = (const float*)d_in[20];
  const float* bih0  = (const float*)d_in[21];
  const float* bhh0  = (const float*)d_in[22];
  const float* Wih1  = (const float*)d_in[23];
  const float* Whh1  = (const float*)d_in[24];
  const float* bih1  = (const float*)d_in[25];
  const float* bhh1  = (const float*)d_in[26];
  const float* att_w = (const float*)d_in[27];
  const float* fc1W  = (const float*)d_in[28];
  const float* fc1b  = (const float*)d_in[29];
  const float* fc2W  = (const float*)d_in[30];
  const float* fc2b  = (const float*)d_in[31];
  float* out = (float*)d_out;

  char* w = (char*)d_ws;
  auto alloc = [&](size_t bytes) -> char* {
    char* p = w;
    w += (bytes + 255) & ~(size_t)255;
    return p;
  };

  float* consts  = (float*)alloc(8 * 4);
  float* scp     = (float*)alloc(3 * 4);
  float* rowsums = (float*)alloc(3000 * 4);
  u16*   Gbuf    = (u16*)alloc((size_t)3000000 * 2);
  u16*   Sbf     = (u16*)alloc((size_t)1024 * 1024 * 2);
  u16*   xbf     = (u16*)alloc((size_t)384000 * 2);
  u16*   fusWbf  = (u16*)alloc((size_t)32000 * 2);
  u16*   Wih0b   = (u16*)alloc((size_t)55296 * 2);
  u16*   Whh0b   = (u16*)alloc((size_t)110592 * 2);
  u16*   Wih1b   = (u16*)alloc((size_t)110592 * 2);
  u16*   Whh1b   = (u16*)alloc((size_t)110592 * 2);
  u16*   w1s     = (u16*)alloc((size_t)192 * 576 * 2);
  u16*   W2s     = (u16*)alloc((size_t)96 * 192 * 2);
  float4* cwpk   = (float4*)alloc((size_t)96 * 16);
  float* fusWT   = (float*)alloc((size_t)32000 * 4);
  float* yt      = (float*)alloc((size_t)384000 * 4);
  u16*   h2t     = (u16*)alloc((size_t)36864 * 1024 * 2);  // 75.5 MB; states/FC alias later
  u16*   Gg      = (u16*)alloc((size_t)36864000 * 2);      // 73.7 MB
  float* Nv      = (float*)alloc((size_t)6144000 * 4);
  float* Mb0     = (float*)alloc((size_t)32000 * 4);
  float* Mb1     = (float*)alloc((size_t)32000 * 4);
  float* Lb0     = (float*)alloc((size_t)32000 * 4);
  float* Lb1     = (float*)alloc((size_t)32000 * 4);
  float* sc0     = (float*)alloc((size_t)32000 * 4);
  float* sc1     = (float*)alloc((size_t)32000 * 4);
  float* sc2     = (float*)alloc((size_t)32000 * 4);

  // state buffers alias h2t region (dead after k_bigemm): h0 x2, h1 x3
  u16* h0s[2] = { h2t,                    h2t + (size_t)6144000 };
  u16* h1s[3] = { h2t + (size_t)12288000, h2t + (size_t)18432000, h2t + (size_t)24576000 };
  // FC-head aliases (h1s[2] read by k_ctxsplit before fc1 writes hfc — stream-ordered)
  u16*   ctxs = h2t;
  float* hfc  = (float*)(h2t + (size_t)18432000);

  k_prep<<<4250, 256, 0, stream>>>(x, fus_W, Wih0, Whh0, Wih1, Whh1, gcn_W1, gcn_b1,
                                   gcn_W2, ln1g, ln1b, fc1W,
                                   xbf, fusWbf, Wih0b, Whh0b, Wih1b, Whh1b, W2s, cwpk,
                                   scp, w1s, fusWT, h2t, sc0, sc1, sc2, consts);
  k_adjrow<<<1000, 256, 0, stream>>>(A, FSP, DSP, E1, E2, beta1, beta2,
                                     fusWT, fus_b, fus_v, Gbuf, rowsums, scp);
  k_shat<<<4000, 256, 0, stream>>>(Gbuf, scp, rowsums, Sbf);
  gemm_nt<0><<<dim3(6, 8), 256, 0, stream>>>(Sbf, 1024, xbf, 1000, yt, 384, 1000, 384, 1000, nullptr);
  k_h2gemm<<<3000, 256, 0, stream>>>(yt, cwpk, W2s, consts, h2t);
  // Gg = LN2( S @ h2t^T + b2 )  (73.7 GFLOP, 128x192 tile, wave-local LN2)
  k_bigemm<<<1536, 256, 0, stream>>>(Sbf, h2t, gcn_b2, ln2g, ln2b, Gg);

  // ---- merged GRU: 13 launches; layer0(u)+fold(u-2) || layer1(u-1) ----
  GruArgs ga;
  ga.Gg = Gg; ga.Wih0 = Wih0b; ga.Whh0 = Whh0b; ga.Wih1 = Wih1b; ga.Whh1 = Whh1b;
  ga.bih0 = bih0; ga.bhh0 = bhh0; ga.bih1 = bih1; ga.bhh1 = bhh1; ga.att_w = att_w;
  ga.h0[0] = h0s[0]; ga.h0[1] = h0s[1];
  ga.h1[0] = h1s[0]; ga.h1[1] = h1s[1]; ga.h1[2] = h1s[2];
  ga.M[0] = Mb0; ga.M[1] = Mb1; ga.L[0] = Lb0; ga.L[1] = Lb1;
  ga.s[0] = sc0; ga.s[1] = sc1; ga.s[2] = sc2;
  ga.Nv = Nv;
  for (int u = 0; u <= 12; ++u)
    k_gru2<<<dim3(12, 250), 256, 0, stream>>>(ga, u);

  // FC head: ctxsplit with fused final pool (tp=11: h1s[2], sc2, Mb0/Lb0)
  k_ctxsplit<<<24000, 256, 0, stream>>>(Nv, h1s[2], sc2, Mb0, Lb0, ctxs);
  gemm_nt<3><<<dim3(3, 250), 256, 0, stream>>>(ctxs, 576, w1s, 576, hfc, 192, 32000, 192, 576, fc1b);
  k_fc2<<<2000, 192, 0, stream>>>(hfc, fc2W, fc2b, out);
}